// Round 1
// baseline (1850.557 us; speedup 1.0000x reference)
//
#include <hip/hip_runtime.h>

// ---------------------------------------------------------------------------
// DecoderLayer on MI355X: rmsnorm -> QKVZ proj -> qk-norm+rope -> causal GQA
// attention (sigmoid-gated) -> Wo + residual -> rmsnorm -> SwiGLU MLP + residual
// GEMMs: bf16 MFMA 16x16x32, 128x128 tiles, global_load_lds staging.
// Attention: f32 VALU flash-style (correctness-first this round).
// ---------------------------------------------------------------------------

typedef __attribute__((ext_vector_type(4))) float  f32x4;
typedef __attribute__((ext_vector_type(8))) short  s16x8;
typedef __attribute__((ext_vector_type(4))) unsigned short u16x4;

#define DEVI static __device__ __forceinline__

DEVI unsigned short f2bf(float f) {
  union { float f; unsigned u; } a; a.f = f;
  unsigned r = a.u + 0x7FFFu + ((a.u >> 16) & 1u);   // round-to-nearest-even
  return (unsigned short)(r >> 16);
}

// global -> LDS async copy, 16B per lane. LDS dest must be wave-uniform base;
// HW adds lane*16. Generic->AS3 cast via integer truncation (low 32 bits of a
// flat shared address are the LDS offset).
DEVI void gload16(const void* g, void* l) {
  __builtin_amdgcn_global_load_lds(
      (const __attribute__((address_space(1))) unsigned int*)(unsigned long long)g,
      (__attribute__((address_space(3))) unsigned int*)(unsigned int)(unsigned long long)l,
      16, 0, 0);
}

// ---------------------------------------------------------------------------
// f32 -> bf16 conversion (vectorized)
// ---------------------------------------------------------------------------
__global__ void k_f32_to_bf16(const float* __restrict__ src,
                              unsigned short* __restrict__ dst, int n4) {
  int i = blockIdx.x * blockDim.x + threadIdx.x;
  int stride = gridDim.x * blockDim.x;
  for (; i < n4; i += stride) {
    f32x4 v = ((const f32x4*)src)[i];
    u16x4 o;
    o.x = f2bf(v.x); o.y = f2bf(v.y); o.z = f2bf(v.z); o.w = f2bf(v.w);
    ((u16x4*)dst)[i] = o;
  }
}

// ---------------------------------------------------------------------------
// Row RMSNorm over H=2048 (f32 in, bf16 out): out = x*rsqrt(mean(x^2)+eps)*(1+w)
// ---------------------------------------------------------------------------
__global__ __launch_bounds__(256) void k_rmsnorm(const float* __restrict__ x,
                                                 const float* __restrict__ w,
                                                 unsigned short* __restrict__ out) {
  const int row = blockIdx.x, t = threadIdx.x;
  const f32x4* xr = (const f32x4*)(x + (size_t)row * 2048);
  f32x4 a = xr[t * 2], b = xr[t * 2 + 1];
  float ss = a.x*a.x + a.y*a.y + a.z*a.z + a.w*a.w
           + b.x*b.x + b.y*b.y + b.z*b.z + b.w*b.w;
#pragma unroll
  for (int m = 32; m; m >>= 1) ss += __shfl_xor(ss, m);
  __shared__ float sred[4];
  if ((t & 63) == 0) sred[t >> 6] = ss;
  __syncthreads();
  float tot = sred[0] + sred[1] + sred[2] + sred[3];
  float r = rsqrtf(tot * (1.0f / 2048.0f) + 1e-6f);
  const f32x4* wr = (const f32x4*)w;
  f32x4 w1 = wr[t * 2], w2 = wr[t * 2 + 1];
  u16x4 o1, o2;
  o1.x = f2bf(a.x * r * (1.f + w1.x)); o1.y = f2bf(a.y * r * (1.f + w1.y));
  o1.z = f2bf(a.z * r * (1.f + w1.z)); o1.w = f2bf(a.w * r * (1.f + w1.w));
  o2.x = f2bf(b.x * r * (1.f + w2.x)); o2.y = f2bf(b.y * r * (1.f + w2.y));
  o2.z = f2bf(b.z * r * (1.f + w2.z)); o2.w = f2bf(b.w * r * (1.f + w2.w));
  u16x4* od = (u16x4*)(out + (size_t)row * 2048);
  od[t * 2] = o1; od[t * 2 + 1] = o2;
}

// ---------------------------------------------------------------------------
// RoPE cos/sin table: [1024][64] each
// ---------------------------------------------------------------------------
__global__ void k_rope_table(float* __restrict__ cosT, float* __restrict__ sinT) {
  int i = blockIdx.x * blockDim.x + threadIdx.x;   // 65536
  int tpos = i >> 6, f = i & 63;
  double inv = exp(-0.14391156831212787 * (double)f);  // ln(10000)/64
  float ang = (float)tpos * (float)inv;                // f32, like reference
  cosT[i] = cosf(ang);
  sinT[i] = sinf(ang);
}

// ---------------------------------------------------------------------------
// Per-head RMSNorm (HD=128) + RoPE, in place on q [4096,2048] and k [4096,512]
// One wave per (token, head). 20 heads per token (16 q + 4 k).
// ---------------------------------------------------------------------------
__global__ __launch_bounds__(256) void k_qknorm_rope(float* __restrict__ Qb,
                                                     float* __restrict__ Kb,
                                                     const float* __restrict__ qw,
                                                     const float* __restrict__ kw,
                                                     const float* __restrict__ cosT,
                                                     const float* __restrict__ sinT) {
  int gid = blockIdx.x * 4 + (threadIdx.x >> 6);
  int lane = threadIdx.x & 63;
  int tok = gid / 20, hh = gid % 20;
  float* p; const float* w;
  if (hh < 16) { p = Qb + (size_t)tok * 2048 + hh * 128;       w = qw; }
  else         { p = Kb + (size_t)tok * 512 + (hh - 16) * 128; w = kw; }
  float x1 = p[lane], x2 = p[lane + 64];
  float ss = x1 * x1 + x2 * x2;
#pragma unroll
  for (int m = 1; m < 64; m <<= 1) ss += __shfl_xor(ss, m);
  float r = rsqrtf(ss * (1.0f / 128.0f) + 1e-6f);
  float n1 = x1 * r * (1.f + w[lane]);
  float n2 = x2 * r * (1.f + w[lane + 64]);
  int s = tok & 1023;
  float c = cosT[s * 64 + lane], sn = sinT[s * 64 + lane];
  p[lane]      = n1 * c - n2 * sn;
  p[lane + 64] = n2 * c + n1 * sn;
}

// ---------------------------------------------------------------------------
// GEMM  C[M,N] = A[M,K] (bf16) . B[N,K]^T (bf16), f32 accumulate via MFMA.
// EPI 0: store f32.  EPI 1: store f32 + residual.  EPI 2: dual-B, store
// bf16( silu(accB) * accB2 ).
// 128x128 tile, BK=32, 256 threads = 4 waves in 2x2, 4x4 16x16 frags each.
// ---------------------------------------------------------------------------
template <int EPI>
__global__ __launch_bounds__(256) void k_gemm_bt(
    const unsigned short* __restrict__ A, const unsigned short* __restrict__ B,
    const unsigned short* __restrict__ B2, float* __restrict__ Cf,
    unsigned short* __restrict__ Cb, const float* __restrict__ res,
    int M, int N, int K) {
  __shared__ unsigned short As[128 * 32];
  __shared__ unsigned short Bs[128 * 32];
  __shared__ unsigned short Bs2[(EPI == 2) ? 128 * 32 : 8];

  const int t = threadIdx.x, lane = t & 63, w = t >> 6;
  const int wr = w >> 1, wc = w & 1;
  const int m0 = blockIdx.y * 128, n0 = blockIdx.x * 128;

  f32x4 acc[4][4] = {};
  f32x4 acc2[4][4] = {};

  const int srow = lane >> 2;            // staging row within 16-row strip
  const int scol = (lane & 3) * 8;       // staging col (bf16 elems)

  for (int kk = 0; kk < K; kk += 32) {
#pragma unroll
    for (int r = 0; r < 2; ++r) {
      int row = 16 * w + srow + 64 * r;
      gload16(A + (size_t)(m0 + row) * K + kk + scol, (void*)&As[w * 512 + r * 2048]);
      gload16(B + (size_t)(n0 + row) * K + kk + scol, (void*)&Bs[w * 512 + r * 2048]);
      if constexpr (EPI == 2)
        gload16(B2 + (size_t)(n0 + row) * K + kk + scol, (void*)&Bs2[w * 512 + r * 2048]);
    }
    __syncthreads();

    s16x8 af[4], bf_[4], b2f[4];
#pragma unroll
    for (int i = 0; i < 4; ++i) {
      af[i]  = *(const s16x8*)&As[(wr * 64 + i * 16 + (lane & 15)) * 32 + (lane >> 4) * 8];
      bf_[i] = *(const s16x8*)&Bs[(wc * 64 + i * 16 + (lane & 15)) * 32 + (lane >> 4) * 8];
      if constexpr (EPI == 2)
        b2f[i] = *(const s16x8*)&Bs2[(wc * 64 + i * 16 + (lane & 15)) * 32 + (lane >> 4) * 8];
    }
#pragma unroll
    for (int mi = 0; mi < 4; ++mi)
#pragma unroll
      for (int ni = 0; ni < 4; ++ni) {
        acc[mi][ni] = __builtin_amdgcn_mfma_f32_16x16x32_bf16(af[mi], bf_[ni], acc[mi][ni], 0, 0, 0);
        if constexpr (EPI == 2)
          acc2[mi][ni] = __builtin_amdgcn_mfma_f32_16x16x32_bf16(af[mi], b2f[ni], acc2[mi][ni], 0, 0, 0);
      }
    __syncthreads();
  }

  // epilogue: C/D layout col = lane&15, row = (lane>>4)*4 + reg
  const int er = (lane >> 4) * 4;
  const int ec = lane & 15;
#pragma unroll
  for (int mi = 0; mi < 4; ++mi)
#pragma unroll
    for (int ni = 0; ni < 4; ++ni) {
      int col = n0 + wc * 64 + ni * 16 + ec;
#pragma unroll
      for (int j = 0; j < 4; ++j) {
        int row = m0 + wr * 64 + mi * 16 + er + j;
        size_t idx = (size_t)row * N + col;
        float g = acc[mi][ni][j];
        if constexpr (EPI == 0) {
          Cf[idx] = g;
        } else if constexpr (EPI == 1) {
          Cf[idx] = g + res[idx];
        } else {
          float u = acc2[mi][ni][j];
          float sg = g / (1.f + __expf(-g));   // silu
          Cb[idx] = f2bf(sg * u);
        }
      }
    }
}

// ---------------------------------------------------------------------------
// Causal GQA attention, f32, flash-style. One block = 32 q-rows of one (b,h).
// K/V tiles of 64 keys staged in LDS. Epilogue fuses sigmoid(z) gate and
// writes bf16 [token, h*128+d] for the Wo GEMM.
// ---------------------------------------------------------------------------
__global__ __launch_bounds__(256) void k_attn(const float* __restrict__ Q,
                                              const float* __restrict__ K,
                                              const float* __restrict__ V,
                                              const float* __restrict__ Z,
                                              unsigned short* __restrict__ AO) {
  const int t = threadIdx.x;
  const int qs0 = blockIdx.x * 32;
  const int h = blockIdx.y, b = blockIdx.z;
  const int kv = h >> 2;

  __shared__ float Qs[32][132];
  __shared__ float Ks[64][132];    // K tile, then reused for V tile
  __shared__ float SP[32][68];     // scores -> probabilities
  __shared__ float mrow[32], lrow[32], rrow[32];

  {  // load Q tile (32 x 128)
    int r = t >> 3, c0 = (t & 7) * 16;
    const f32x4* src = (const f32x4*)(Q + ((size_t)(b * 1024 + qs0 + r)) * 2048 + h * 128 + c0);
    f32x4* dst = (f32x4*)&Qs[r][c0];
#pragma unroll
    for (int i = 0; i < 4; ++i) dst[i] = src[i];
  }
  if (t < 32) { mrow[t] = -1e30f; lrow[t] = 0.f; }

  const int r2 = t >> 4;      // 0..15 -> rows 2r2, 2r2+1
  const int dq8 = t & 15;     // dim groups 4*dq8 and 64+4*dq8
  f32x4 oa0 = {0, 0, 0, 0}, oa1 = oa0, ob0 = oa0, ob1 = oa0;

  const int ntiles = ((qs0 + 31) >> 6) + 1;
  const float scale = 0.088388347648318447f;   // 1/sqrt(128)

  for (int tile = 0; tile < ntiles; ++tile) {
    const int j0 = tile * 64;
    __syncthreads();   // previous pass done with Ks
    {  // load K tile (64 x 128)
      int jj = t >> 2, c0 = (t & 3) * 32;
      const f32x4* src = (const f32x4*)(K + ((size_t)(b * 1024 + j0 + jj)) * 512 + kv * 128 + c0);
      f32x4* dst = (f32x4*)&Ks[jj][c0];
#pragma unroll
      for (int i = 0; i < 8; ++i) dst[i] = src[i];
    }
    __syncthreads();
    {  // scores: 2 rows x 4 keys per thread; keys j = jq + 16*jj
      const int rp = t >> 4, jq = t & 15;
      const f32x4* qa = (const f32x4*)&Qs[2 * rp][0];
      const f32x4* qb = (const f32x4*)&Qs[2 * rp + 1][0];
      const f32x4* k0 = (const f32x4*)&Ks[jq][0];
      const f32x4* k1 = (const f32x4*)&Ks[jq + 16][0];
      const f32x4* k2 = (const f32x4*)&Ks[jq + 32][0];
      const f32x4* k3 = (const f32x4*)&Ks[jq + 48][0];
      f32x4 s0 = {0, 0, 0, 0}, s1 = s0, s2 = s0, s3 = s0, s4 = s0, s5 = s0, s6 = s0, s7 = s0;
#pragma unroll 8
      for (int d = 0; d < 32; ++d) {
        f32x4 A0 = qa[d], A1 = qb[d];
        f32x4 B0 = k0[d], B1 = k1[d], B2v = k2[d], B3 = k3[d];
        s0 += A0 * B0; s1 += A0 * B1; s2 += A0 * B2v; s3 += A0 * B3;
        s4 += A1 * B0; s5 += A1 * B1; s6 += A1 * B2v; s7 += A1 * B3;
      }
      float d0 = (s0.x + s0.y) + (s0.z + s0.w);
      float d1 = (s1.x + s1.y) + (s1.z + s1.w);
      float d2 = (s2.x + s2.y) + (s2.z + s2.w);
      float d3 = (s3.x + s3.y) + (s3.z + s3.w);
      float d4 = (s4.x + s4.y) + (s4.z + s4.w);
      float d5 = (s5.x + s5.y) + (s5.z + s5.w);
      float d6 = (s6.x + s6.y) + (s6.z + s6.w);
      float d7 = (s7.x + s7.y) + (s7.z + s7.w);
      int qg0 = qs0 + 2 * rp, qg1 = qg0 + 1;
      SP[2 * rp][jq]      = (j0 + jq      <= qg0) ? d0 * scale : -1e30f;
      SP[2 * rp][jq + 16] = (j0 + jq + 16 <= qg0) ? d1 * scale : -1e30f;
      SP[2 * rp][jq + 32] = (j0 + jq + 32 <= qg0) ? d2 * scale : -1e30f;
      SP[2 * rp][jq + 48] = (j0 + jq + 48 <= qg0) ? d3 * scale : -1e30f;
      SP[2 * rp + 1][jq]      = (j0 + jq      <= qg1) ? d4 * scale : -1e30f;
      SP[2 * rp + 1][jq + 16] = (j0 + jq + 16 <= qg1) ? d5 * scale : -1e30f;
      SP[2 * rp + 1][jq + 32] = (j0 + jq + 32 <= qg1) ? d6 * scale : -1e30f;
      SP[2 * rp + 1][jq + 48] = (j0 + jq + 48 <= qg1) ? d7 * scale : -1e30f;
    }
    __syncthreads();
    {  // online softmax update: 8 threads per row
      int r = t >> 3, js = t & 7;
      float sv[8];
      float lmax = -1e30f;
#pragma unroll
      for (int i = 0; i < 8; ++i) { sv[i] = SP[r][js + 8 * i]; lmax = fmaxf(lmax, sv[i]); }
#pragma unroll
      for (int m = 1; m < 8; m <<= 1) lmax = fmaxf(lmax, __shfl_xor(lmax, m));
      float mold = mrow[r];
      float mnew = fmaxf(mold, lmax);
      float ps = 0.f;
#pragma unroll
      for (int i = 0; i < 8; ++i) {
        float p = __expf(sv[i] - mnew);
        SP[r][js + 8 * i] = p;
        ps += p;
      }
#pragma unroll
      for (int m = 1; m < 8; m <<= 1) ps += __shfl_xor(ps, m);
      if (js == 0) {
        float rs = __expf(mold - mnew);
        rrow[r] = rs;
        lrow[r] = lrow[r] * rs + ps;
        mrow[r] = mnew;
      }
    }
    __syncthreads();
    {  // load V tile over Ks
      int jj = t >> 2, c0 = (t & 3) * 32;
      const f32x4* src = (const f32x4*)(V + ((size_t)(b * 1024 + j0 + jj)) * 512 + kv * 128 + c0);
      f32x4* dst = (f32x4*)&Ks[jj][c0];
#pragma unroll
      for (int i = 0; i < 8; ++i) dst[i] = src[i];
    }
    __syncthreads();
    {  // accumulate O += P . V, with rescale
      float ra = rrow[2 * r2], rb = rrow[2 * r2 + 1];
      oa0 *= ra; ob0 *= ra; oa1 *= rb; ob1 *= rb;
#pragma unroll 4
      for (int j = 0; j < 64; ++j) {
        float p0 = SP[2 * r2][j], p1 = SP[2 * r2 + 1][j];
        f32x4 va = *(const f32x4*)&Ks[j][4 * dq8];
        f32x4 vb = *(const f32x4*)&Ks[j][64 + 4 * dq8];
        oa0 += p0 * va; ob0 += p0 * vb;
        oa1 += p1 * va; ob1 += p1 * vb;
      }
    }
  }

  // epilogue: normalize, sigmoid(z) gate, bf16 store
  float la = 1.f / lrow[2 * r2], lb = 1.f / lrow[2 * r2 + 1];
  size_t base0 = ((size_t)(b * 1024 + qs0 + 2 * r2)) * 2048 + h * 128;
  size_t base1 = base0 + 2048;
  const int ca = 4 * dq8, cb = 64 + 4 * dq8;
  f32x4 o[4] = {oa0 * la, ob0 * la, oa1 * lb, ob1 * lb};
  size_t idxs[4] = {base0 + ca, base0 + cb, base1 + ca, base1 + cb};
#pragma unroll
  for (int i = 0; i < 4; ++i) {
    f32x4 z = *(const f32x4*)(Z + idxs[i]);
    u16x4 u;
    u.x = f2bf(o[i].x / (1.f + __expf(-z.x)));
    u.y = f2bf(o[i].y / (1.f + __expf(-z.y)));
    u.z = f2bf(o[i].z / (1.f + __expf(-z.z)));
    u.w = f2bf(o[i].w / (1.f + __expf(-z.w)));
    *(u16x4*)(AO + idxs[i]) = u;
  }
}

// ---------------------------------------------------------------------------
// launcher
// ---------------------------------------------------------------------------
extern "C" void kernel_launch(void* const* d_in, const int* in_sizes, int n_in,
                              void* d_out, int out_size, void* d_ws, size_t ws_size,
                              hipStream_t stream) {
  const float* x       = (const float*)d_in[0];
  const float* in_ln   = (const float*)d_in[1];
  const float* Wq      = (const float*)d_in[2];
  const float* Wk      = (const float*)d_in[3];
  const float* Wv      = (const float*)d_in[4];
  const float* Wz      = (const float*)d_in[5];
  const float* Wo      = (const float*)d_in[6];
  const float* qn_w    = (const float*)d_in[7];
  const float* kn_w    = (const float*)d_in[8];
  const float* post_ln = (const float*)d_in[9];
  const float* Wg      = (const float*)d_in[10];
  const float* Wu      = (const float*)d_in[11];
  const float* Wd      = (const float*)d_in[12];

  const int T = 4096;   // B*S tokens

  char* ws = (char*)d_ws;
  size_t off = 0;
  auto alloc = [&](size_t bytes) -> void* {
    off = (off + 255) & ~(size_t)255;
    void* p = ws + off;
    off += bytes;
    return p;
  };

  unsigned short* Wq_b = (unsigned short*)alloc((size_t)2048 * 2048 * 2);
  unsigned short* Wk_b = (unsigned short*)alloc((size_t)512 * 2048 * 2);
  unsigned short* Wv_b = (unsigned short*)alloc((size_t)512 * 2048 * 2);
  unsigned short* Wz_b = (unsigned short*)alloc((size_t)2048 * 2048 * 2);
  unsigned short* Wo_b = (unsigned short*)alloc((size_t)2048 * 2048 * 2);
  unsigned short* Wg_b = (unsigned short*)alloc((size_t)8192 * 2048 * 2);
  unsigned short* Wu_b = (unsigned short*)alloc((size_t)8192 * 2048 * 2);
  unsigned short* Wd_b = (unsigned short*)alloc((size_t)2048 * 8192 * 2);

  float* qbuf = (float*)alloc((size_t)T * 2048 * 4);
  float* kbuf = (float*)alloc((size_t)T * 512 * 4);
  float* vbuf = (float*)alloc((size_t)T * 512 * 4);
  float* zbuf = (float*)alloc((size_t)T * 2048 * 4);
  unsigned short* h_bf = (unsigned short*)alloc((size_t)T * 2048 * 2);
  float* x2 = (float*)alloc((size_t)T * 2048 * 4);
  unsigned short* h2_bf = (unsigned short*)alloc((size_t)T * 2048 * 2);
  float* cosT = (float*)alloc((size_t)1024 * 64 * 4);
  float* sinT = (float*)alloc((size_t)1024 * 64 * 4);

  // aliases: lifetimes are disjoint (stream-ordered)
  unsigned short* ao_bf = h_bf;                  // after h consumed by QKVZ GEMMs
  unsigned short* gu_bf = (unsigned short*)qbuf; // after attention consumed q/k/v/z

  auto cvt = [&](const float* s, unsigned short* d, size_t n) {
    int n4 = (int)(n / 4);
    int blocks = (n4 + 255) / 256;
    if (blocks > 2048) blocks = 2048;
    k_f32_to_bf16<<<blocks, 256, 0, stream>>>(s, d, n4);
  };
  cvt(Wq, Wq_b, (size_t)2048 * 2048);
  cvt(Wk, Wk_b, (size_t)512 * 2048);
  cvt(Wv, Wv_b, (size_t)512 * 2048);
  cvt(Wz, Wz_b, (size_t)2048 * 2048);
  cvt(Wo, Wo_b, (size_t)2048 * 2048);
  cvt(Wg, Wg_b, (size_t)8192 * 2048);
  cvt(Wu, Wu_b, (size_t)8192 * 2048);
  cvt(Wd, Wd_b, (size_t)2048 * 8192);

  k_rope_table<<<256, 256, 0, stream>>>(cosT, sinT);

  // h = rmsnorm(x, in_ln)
  k_rmsnorm<<<T, 256, 0, stream>>>(x, in_ln, h_bf);

  // QKVZ projections
  k_gemm_bt<0><<<dim3(16, 32), 256, 0, stream>>>(h_bf, Wq_b, nullptr, qbuf, nullptr, nullptr, T, 2048, 2048);
  k_gemm_bt<0><<<dim3(4, 32), 256, 0, stream>>>(h_bf, Wk_b, nullptr, kbuf, nullptr, nullptr, T, 512, 2048);
  k_gemm_bt<0><<<dim3(4, 32), 256, 0, stream>>>(h_bf, Wv_b, nullptr, vbuf, nullptr, nullptr, T, 512, 2048);
  k_gemm_bt<0><<<dim3(16, 32), 256, 0, stream>>>(h_bf, Wz_b, nullptr, zbuf, nullptr, nullptr, T, 2048, 2048);

  // per-head q/k RMSNorm + RoPE (in place)
  k_qknorm_rope<<<20480, 256, 0, stream>>>(qbuf, kbuf, qn_w, kn_w, cosT, sinT);

  // causal GQA attention + sigmoid(z) gate -> ao_bf
  k_attn<<<dim3(32, 16, 4), 256, 0, stream>>>(qbuf, kbuf, vbuf, zbuf, ao_bf);

  // x2 = x + ao @ Wo^T
  k_gemm_bt<1><<<dim3(16, 32), 256, 0, stream>>>(ao_bf, Wo_b, nullptr, x2, nullptr, x, T, 2048, 2048);

  // h2 = rmsnorm(x2, post_ln)
  k_rmsnorm<<<T, 256, 0, stream>>>(x2, post_ln, h2_bf);

  // gu = silu(h2 @ Wg^T) * (h2 @ Wu^T)   (bf16)
  k_gemm_bt<2><<<dim3(64, 32), 256, 0, stream>>>(h2_bf, Wg_b, Wu_b, nullptr, gu_bf, nullptr, T, 8192, 2048);

  // out = x2 + gu @ Wd^T
  k_gemm_bt<1><<<dim3(16, 32), 256, 0, stream>>>(gu_bf, Wd_b, nullptr, (float*)d_out, nullptr, x2, T, 2048, 8192);
}

// Round 2
// 1333.198 us; speedup vs baseline: 1.3881x; 1.3881x over previous
//
#include <hip/hip_runtime.h>

// ---------------------------------------------------------------------------
// DecoderLayer on MI355X: rmsnorm -> QKVZ proj -> qk-norm+rope -> causal GQA
// attention (sigmoid-gated, bf16 MFMA flash) -> Wo + residual -> rmsnorm ->
// SwiGLU MLP + residual.
// GEMMs: bf16 MFMA 16x16x32, 128x128 tiles, global_load_lds staging, XCD swizzle.
// ---------------------------------------------------------------------------

typedef __attribute__((ext_vector_type(4))) float  f32x4;
typedef __attribute__((ext_vector_type(8))) short  s16x8;
typedef __attribute__((ext_vector_type(4))) unsigned short u16x4;

#define DEVI static __device__ __forceinline__

DEVI unsigned short f2bf(float f) {
  union { float f; unsigned u; } a; a.f = f;
  unsigned r = a.u + 0x7FFFu + ((a.u >> 16) & 1u);   // round-to-nearest-even
  return (unsigned short)(r >> 16);
}

// global -> LDS async copy, 16B per lane. LDS dest is wave-uniform base + lane*16.
DEVI void gload16(const void* g, void* l) {
  __builtin_amdgcn_global_load_lds(
      (const __attribute__((address_space(1))) unsigned int*)(unsigned long long)g,
      (__attribute__((address_space(3))) unsigned int*)(unsigned int)(unsigned long long)l,
      16, 0, 0);
}

// ---------------------------------------------------------------------------
// f32 -> bf16 conversion (vectorized)
// ---------------------------------------------------------------------------
__global__ void k_f32_to_bf16(const float* __restrict__ src,
                              unsigned short* __restrict__ dst, int n4) {
  int i = blockIdx.x * blockDim.x + threadIdx.x;
  int stride = gridDim.x * blockDim.x;
  for (; i < n4; i += stride) {
    f32x4 v = ((const f32x4*)src)[i];
    u16x4 o;
    o.x = f2bf(v.x); o.y = f2bf(v.y); o.z = f2bf(v.z); o.w = f2bf(v.w);
    ((u16x4*)dst)[i] = o;
  }
}

// ---------------------------------------------------------------------------
// Row RMSNorm over H=2048 (f32 in, bf16 out)
// ---------------------------------------------------------------------------
__global__ __launch_bounds__(256) void k_rmsnorm(const float* __restrict__ x,
                                                 const float* __restrict__ w,
                                                 unsigned short* __restrict__ out) {
  const int row = blockIdx.x, t = threadIdx.x;
  const f32x4* xr = (const f32x4*)(x + (size_t)row * 2048);
  f32x4 a = xr[t * 2], b = xr[t * 2 + 1];
  float ss = a.x*a.x + a.y*a.y + a.z*a.z + a.w*a.w
           + b.x*b.x + b.y*b.y + b.z*b.z + b.w*b.w;
#pragma unroll
  for (int m = 32; m; m >>= 1) ss += __shfl_xor(ss, m);
  __shared__ float sred[4];
  if ((t & 63) == 0) sred[t >> 6] = ss;
  __syncthreads();
  float tot = sred[0] + sred[1] + sred[2] + sred[3];
  float r = rsqrtf(tot * (1.0f / 2048.0f) + 1e-6f);
  const f32x4* wr = (const f32x4*)w;
  f32x4 w1 = wr[t * 2], w2 = wr[t * 2 + 1];
  u16x4 o1, o2;
  o1.x = f2bf(a.x * r * (1.f + w1.x)); o1.y = f2bf(a.y * r * (1.f + w1.y));
  o1.z = f2bf(a.z * r * (1.f + w1.z)); o1.w = f2bf(a.w * r * (1.f + w1.w));
  o2.x = f2bf(b.x * r * (1.f + w2.x)); o2.y = f2bf(b.y * r * (1.f + w2.y));
  o2.z = f2bf(b.z * r * (1.f + w2.z)); o2.w = f2bf(b.w * r * (1.f + w2.w));
  u16x4* od = (u16x4*)(out + (size_t)row * 2048);
  od[t * 2] = o1; od[t * 2 + 1] = o2;
}

// ---------------------------------------------------------------------------
// RoPE cos/sin table: [1024][64] each
// ---------------------------------------------------------------------------
__global__ void k_rope_table(float* __restrict__ cosT, float* __restrict__ sinT) {
  int i = blockIdx.x * blockDim.x + threadIdx.x;   // 65536
  int tpos = i >> 6, f = i & 63;
  double inv = exp(-0.14391156831212787 * (double)f);  // ln(10000)/64
  float ang = (float)tpos * (float)inv;
  cosT[i] = cosf(ang);
  sinT[i] = sinf(ang);
}

// ---------------------------------------------------------------------------
// Per-head RMSNorm (HD=128) + RoPE on q/k (f32 in), bf16 out.
// One wave per (token, head). 20 heads per token (16 q + 4 k).
// ---------------------------------------------------------------------------
__global__ __launch_bounds__(256) void k_qknorm_rope(
    const float* __restrict__ Qf, const float* __restrict__ Kf,
    unsigned short* __restrict__ Qo, unsigned short* __restrict__ Ko,
    const float* __restrict__ qw, const float* __restrict__ kw,
    const float* __restrict__ cosT, const float* __restrict__ sinT) {
  int gid = blockIdx.x * 4 + (threadIdx.x >> 6);
  int lane = threadIdx.x & 63;
  int tok = gid / 20, hh = gid % 20;
  const float* p; const float* w; unsigned short* o;
  if (hh < 16) { p = Qf + (size_t)tok * 2048 + hh * 128; w = qw;
                 o = Qo + (size_t)tok * 2048 + hh * 128; }
  else         { p = Kf + (size_t)tok * 512 + (hh - 16) * 128; w = kw;
                 o = Ko + (size_t)tok * 512 + (hh - 16) * 128; }
  float x1 = p[lane], x2 = p[lane + 64];
  float ss = x1 * x1 + x2 * x2;
#pragma unroll
  for (int m = 1; m < 64; m <<= 1) ss += __shfl_xor(ss, m);
  float r = rsqrtf(ss * (1.0f / 128.0f) + 1e-6f);
  float n1 = x1 * r * (1.f + w[lane]);
  float n2 = x2 * r * (1.f + w[lane + 64]);
  int s = tok & 1023;
  float c = cosT[s * 64 + lane], sn = sinT[s * 64 + lane];
  o[lane]      = f2bf(n1 * c - n2 * sn);
  o[lane + 64] = f2bf(n2 * c + n1 * sn);
}

// ---------------------------------------------------------------------------
// V transpose: vbuf f32 [4096 tok][512] -> Vt bf16 [(b*4+kv)][128 d][1024 key]
// ---------------------------------------------------------------------------
__global__ __launch_bounds__(256) void k_transpose_v(const float* __restrict__ V,
                                                     unsigned short* __restrict__ Vt) {
  __shared__ unsigned short Vl[128 * 66];
  const int t = threadIdx.x;
  const int key0 = blockIdx.x * 64, kvh = blockIdx.y, b = blockIdx.z;
#pragma unroll
  for (int i = 0; i < 8; ++i) {
    int g = i * 256 + t;                 // 2048 f32x4 granules
    int key = g >> 5, dc = g & 31;
    f32x4 v = *(const f32x4*)&V[(size_t)(b * 1024 + key0 + key) * 512 + kvh * 128 + dc * 4];
#pragma unroll
    for (int j = 0; j < 4; ++j) Vl[(dc * 4 + j) * 66 + key] = f2bf(v[j]);
  }
  __syncthreads();
#pragma unroll
  for (int i = 0; i < 8; ++i) {
    int g = i * 256 + t;                 // 2048 u16x4 granules
    int d = g >> 4, kc = g & 15;
    u16x4 o;
#pragma unroll
    for (int j = 0; j < 4; ++j) o[j] = Vl[d * 66 + kc * 4 + j];
    *(u16x4*)&Vt[((size_t)(b * 4 + kvh) * 128 + d) * 1024 + key0 + kc * 4] = o;
  }
}

// ---------------------------------------------------------------------------
// GEMM  C[M,N] = A[M,K] (bf16) . B[N,K]^T (bf16), f32 accumulate via MFMA.
// EPI 0: store f32.  EPI 1: f32 + residual.  EPI 2: dual-B, bf16(silu(g)*u).
// 128x128 tile, BK=32, 4 waves 2x2, 4x4 frags. Bijective XCD blockIdx swizzle.
// ---------------------------------------------------------------------------
template <int EPI>
__global__ __launch_bounds__(256) void k_gemm_bt(
    const unsigned short* __restrict__ A, const unsigned short* __restrict__ B,
    const unsigned short* __restrict__ B2, float* __restrict__ Cf,
    unsigned short* __restrict__ Cb, const float* __restrict__ res,
    int M, int N, int K) {
  __shared__ unsigned short As[128 * 32];
  __shared__ unsigned short Bs[128 * 32];
  __shared__ unsigned short Bs2[(EPI == 2) ? 128 * 32 : 8];

  const int t = threadIdx.x, lane = t & 63, w = t >> 6;
  const int wr = w >> 1, wc = w & 1;
  // XCD-aware bijective swizzle (nwg % 8 == 0 for all our grids)
  const int nbx = gridDim.x;
  const int nwg = nbx * gridDim.y;
  const int bid = blockIdx.y * nbx + blockIdx.x;
  const int sw = (bid & 7) * (nwg >> 3) + (bid >> 3);
  const int m0 = (sw / nbx) * 128, n0 = (sw % nbx) * 128;

  f32x4 acc[4][4] = {};
  f32x4 acc2[4][4] = {};

  const int srow = lane >> 2;
  const int scol = (lane & 3) * 8;

  for (int kk = 0; kk < K; kk += 32) {
#pragma unroll
    for (int r = 0; r < 2; ++r) {
      int row = 16 * w + srow + 64 * r;
      gload16(A + (size_t)(m0 + row) * K + kk + scol, (void*)&As[w * 512 + r * 2048]);
      gload16(B + (size_t)(n0 + row) * K + kk + scol, (void*)&Bs[w * 512 + r * 2048]);
      if constexpr (EPI == 2)
        gload16(B2 + (size_t)(n0 + row) * K + kk + scol, (void*)&Bs2[w * 512 + r * 2048]);
    }
    __syncthreads();

    s16x8 af[4], bf_[4], b2f[4];
#pragma unroll
    for (int i = 0; i < 4; ++i) {
      af[i]  = *(const s16x8*)&As[(wr * 64 + i * 16 + (lane & 15)) * 32 + (lane >> 4) * 8];
      bf_[i] = *(const s16x8*)&Bs[(wc * 64 + i * 16 + (lane & 15)) * 32 + (lane >> 4) * 8];
      if constexpr (EPI == 2)
        b2f[i] = *(const s16x8*)&Bs2[(wc * 64 + i * 16 + (lane & 15)) * 32 + (lane >> 4) * 8];
    }
#pragma unroll
    for (int mi = 0; mi < 4; ++mi)
#pragma unroll
      for (int ni = 0; ni < 4; ++ni) {
        acc[mi][ni] = __builtin_amdgcn_mfma_f32_16x16x32_bf16(af[mi], bf_[ni], acc[mi][ni], 0, 0, 0);
        if constexpr (EPI == 2)
          acc2[mi][ni] = __builtin_amdgcn_mfma_f32_16x16x32_bf16(af[mi], b2f[ni], acc2[mi][ni], 0, 0, 0);
      }
    __syncthreads();
  }

  const int er = (lane >> 4) * 4;
  const int ec = lane & 15;
#pragma unroll
  for (int mi = 0; mi < 4; ++mi)
#pragma unroll
    for (int ni = 0; ni < 4; ++ni) {
      int col = n0 + wc * 64 + ni * 16 + ec;
#pragma unroll
      for (int j = 0; j < 4; ++j) {
        int row = m0 + wr * 64 + mi * 16 + er + j;
        size_t idx = (size_t)row * N + col;
        float g = acc[mi][ni][j];
        if constexpr (EPI == 0) {
          Cf[idx] = g;
        } else if constexpr (EPI == 1) {
          Cf[idx] = g + res[idx];
        } else {
          float u = acc2[mi][ni][j];
          float sg = g / (1.f + __expf(-g));   // silu
          Cb[idx] = f2bf(sg * u);
        }
      }
    }
}

// ---------------------------------------------------------------------------
// Causal GQA attention, bf16 MFMA flash. Block = 64 q-rows of one (b,h),
// 4 waves x 16 q-rows. Q frags persistent in regs; K [64x128] and V^T [128x64]
// staged via global_load_lds with XOR-granule swizzle (conflict-free ds_read_b128).
// Online softmax in registers; P via per-wave swizzled LDS. Epilogue fuses
// sigmoid(z) gate, writes bf16 [tok][h*128+d].
// ---------------------------------------------------------------------------
__global__ __launch_bounds__(256) void k_attn_mfma(
    const unsigned short* __restrict__ Qb,   // [4096][2048] bf16
    const unsigned short* __restrict__ Kb,   // [4096][512]  bf16
    const unsigned short* __restrict__ Vt,   // [16][128][1024] bf16
    const float* __restrict__ Z,             // [4096][2048] f32
    unsigned short* __restrict__ AO) {       // [4096][2048] bf16
  __shared__ unsigned short Qs[64 * 128];
  __shared__ unsigned short Ks[64 * 128];
  __shared__ unsigned short Vts[128 * 64];
  __shared__ unsigned short Ps[4][16 * 64];

  const int t = threadIdx.x, lane = t & 63, w = t >> 6;
  const int l15 = lane & 15, l4 = lane >> 4;
  const int qt = (int)gridDim.x - 1 - (int)blockIdx.x;   // long blocks first
  const int qs0 = qt * 64;
  const int h = blockIdx.y, b = blockIdx.z;
  const int kv = h >> 2;

  // ---- stage Q tile (64 x 128) with granule swizzle c' = (c&8)|((c&7)^(row&7))
  {
    const unsigned short* qb = Qb + (size_t)(b * 1024 + qs0) * 2048 + h * 128;
#pragma unroll
    for (int r = 0; r < 4; ++r) {
      int row = r * 16 + w * 4 + (lane >> 4);
      int cp = lane & 15;
      int c = (cp & 8) | ((cp & 7) ^ (row & 7));
      gload16(qb + (size_t)row * 2048 + c * 8, (void*)&Qs[(r * 256 + w * 64) * 8]);
    }
  }

  auto stageKV = [&](int j0) {
    const unsigned short* kb = Kb + (size_t)(b * 1024 + j0) * 512 + kv * 128;
#pragma unroll
    for (int r = 0; r < 4; ++r) {
      int row = r * 16 + w * 4 + (lane >> 4);
      int cp = lane & 15;
      int c = (cp & 8) | ((cp & 7) ^ (row & 7));
      gload16(kb + (size_t)row * 512 + c * 8, (void*)&Ks[(r * 256 + w * 64) * 8]);
    }
    const unsigned short* vb = Vt + (size_t)(b * 4 + kv) * 131072 + j0;
#pragma unroll
    for (int r = 0; r < 4; ++r) {
      int row = r * 32 + w * 8 + (lane >> 3);
      int cp = lane & 7;
      int c = cp ^ (row & 7);
      gload16(vb + (size_t)row * 1024 + c * 8, (void*)&Vts[(r * 256 + w * 64) * 8]);
    }
  };

  stageKV(0);
  __syncthreads();   // compiler drains vmcnt before barrier -> Qs/Ks/Vts valid

  // persistent Q fragments: A-row = l15 (q within wave tile), k = l4*8 + ks*32
  s16x8 qf[4];
#pragma unroll
  for (int ks = 0; ks < 4; ++ks) {
    int R = w * 16 + l15;
    int c = ks * 4 + l4;
    int cp = (c & 8) | ((c & 7) ^ (R & 7));
    qf[ks] = *(const s16x8*)&Qs[R * 128 + cp * 8];
  }

  f32x4 O[8] = {};
  f32x4 mrow = {-1e30f, -1e30f, -1e30f, -1e30f};
  f32x4 lrow = {0.f, 0.f, 0.f, 0.f};
  const float scale = 0.088388347648318447f;   // 1/sqrt(128)

  for (int tile = 0; tile <= qt; ++tile) {
    // ---- S = Q . K^T  (C layout: col=key=kt*16+l15, row=q=l4*4+reg)
    f32x4 sc[4] = {};
#pragma unroll
    for (int ks = 0; ks < 4; ++ks) {
#pragma unroll
      for (int kt = 0; kt < 4; ++kt) {
        int R = kt * 16 + l15;
        int c = ks * 4 + l4;
        int cp = (c & 8) | ((c & 7) ^ (R & 7));
        s16x8 kf = *(const s16x8*)&Ks[R * 128 + cp * 8];
        sc[kt] = __builtin_amdgcn_mfma_f32_16x16x32_bf16(qf[ks], kf, sc[kt], 0, 0, 0);
      }
    }
    // ---- mask + scale
    const bool diag = (tile == qt);
#pragma unroll
    for (int kt = 0; kt < 4; ++kt) {
      int key = kt * 16 + l15;
#pragma unroll
      for (int j = 0; j < 4; ++j) {
        float s = sc[kt][j] * scale;
        if (diag && key > (w * 16 + l4 * 4 + j)) s = -1e30f;
        sc[kt][j] = s;
      }
    }
    // ---- online softmax (row = q, reduce across the 16-lane key group)
    f32x4 mt;
#pragma unroll
    for (int j = 0; j < 4; ++j)
      mt[j] = fmaxf(fmaxf(sc[0][j], sc[1][j]), fmaxf(sc[2][j], sc[3][j]));
#pragma unroll
    for (int msk = 1; msk < 16; msk <<= 1)
#pragma unroll
      for (int j = 0; j < 4; ++j) mt[j] = fmaxf(mt[j], __shfl_xor(mt[j], msk));
    f32x4 mnew, rs;
#pragma unroll
    for (int j = 0; j < 4; ++j) {
      mnew[j] = fmaxf(mrow[j], mt[j]);
      rs[j] = __expf(mrow[j] - mnew[j]);
    }
    f32x4 psum = {0.f, 0.f, 0.f, 0.f};
    unsigned short* pw = &Ps[w][0];
#pragma unroll
    for (int kt = 0; kt < 4; ++kt) {
      int kg = kt * 2 + (l15 >> 3), ke = l15 & 7;
#pragma unroll
      for (int j = 0; j < 4; ++j) {
        float p = __expf(sc[kt][j] - mnew[j]);
        psum[j] += p;
        int q = l4 * 4 + j;
        pw[q * 64 + ((kg ^ (q & 7)) * 8) + ke] = f2bf(p);
      }
    }
#pragma unroll
    for (int msk = 1; msk < 16; msk <<= 1)
#pragma unroll
      for (int j = 0; j < 4; ++j) psum[j] += __shfl_xor(psum[j], msk);
    mrow = mnew;
#pragma unroll
    for (int j = 0; j < 4; ++j) lrow[j] = lrow[j] * rs[j] + psum[j];
#pragma unroll
    for (int dt = 0; dt < 8; ++dt) O[dt] *= rs;
    // ---- O += P . V  (A = P rows q, B = V^T rows d; contraction over keys)
#pragma unroll
    for (int js = 0; js < 2; ++js) {
      int cpp = (js * 4 + l4) ^ (l15 & 7);
      s16x8 pf = *(const s16x8*)&Ps[w][l15 * 64 + cpp * 8];
#pragma unroll
      for (int dt = 0; dt < 8; ++dt) {
        int D = dt * 16 + l15;
        s16x8 vf = *(const s16x8*)&Vts[D * 64 + cpp * 8];   // D&7 == l15&7
        O[dt] = __builtin_amdgcn_mfma_f32_16x16x32_bf16(pf, vf, O[dt], 0, 0, 0);
      }
    }
    __syncthreads();                       // all waves done with Ks/Vts
    if (tile < qt) stageKV((tile + 1) * 64);
    __syncthreads();                       // staged tile visible
  }

  // ---- epilogue: normalize, sigmoid(z) gate, bf16 store
  f32x4 linv;
#pragma unroll
  for (int j = 0; j < 4; ++j) linv[j] = 1.f / lrow[j];
  const int tok0 = b * 1024 + qs0 + w * 16 + l4 * 4;
#pragma unroll
  for (int dt = 0; dt < 8; ++dt) {
    int d = dt * 16 + l15;
#pragma unroll
    for (int j = 0; j < 4; ++j) {
      size_t idx = (size_t)(tok0 + j) * 2048 + h * 128 + d;
      float z = Z[idx];
      float o = O[dt][j] * linv[j];
      AO[idx] = f2bf(o / (1.f + __expf(-z)));
    }
  }
}

// ---------------------------------------------------------------------------
// launcher
// ---------------------------------------------------------------------------
extern "C" void kernel_launch(void* const* d_in, const int* in_sizes, int n_in,
                              void* d_out, int out_size, void* d_ws, size_t ws_size,
                              hipStream_t stream) {
  const float* x       = (const float*)d_in[0];
  const float* in_ln   = (const float*)d_in[1];
  const float* Wq      = (const float*)d_in[2];
  const float* Wk      = (const float*)d_in[3];
  const float* Wv      = (const float*)d_in[4];
  const float* Wz      = (const float*)d_in[5];
  const float* Wo      = (const float*)d_in[6];
  const float* qn_w    = (const float*)d_in[7];
  const float* kn_w    = (const float*)d_in[8];
  const float* post_ln = (const float*)d_in[9];
  const float* Wg      = (const float*)d_in[10];
  const float* Wu      = (const float*)d_in[11];
  const float* Wd      = (const float*)d_in[12];

  const int T = 4096;   // B*S tokens

  char* ws = (char*)d_ws;
  size_t off = 0;
  auto alloc = [&](size_t bytes) -> void* {
    off = (off + 255) & ~(size_t)255;
    void* p = ws + off;
    off += bytes;
    return p;
  };

  unsigned short* Wq_b = (unsigned short*)alloc((size_t)2048 * 2048 * 2);
  unsigned short* Wk_b = (unsigned short*)alloc((size_t)512 * 2048 * 2);
  unsigned short* Wv_b = (unsigned short*)alloc((size_t)512 * 2048 * 2);
  unsigned short* Wz_b = (unsigned short*)alloc((size_t)2048 * 2048 * 2);
  unsigned short* Wo_b = (unsigned short*)alloc((size_t)2048 * 2048 * 2);
  unsigned short* Wg_b = (unsigned short*)alloc((size_t)8192 * 2048 * 2);
  unsigned short* Wu_b = (unsigned short*)alloc((size_t)8192 * 2048 * 2);
  unsigned short* Wd_b = (unsigned short*)alloc((size_t)2048 * 8192 * 2);

  float* qbuf = (float*)alloc((size_t)T * 2048 * 4);
  float* kbuf = (float*)alloc((size_t)T * 512 * 4);
  float* vbuf = (float*)alloc((size_t)T * 512 * 4);
  float* zbuf = (float*)alloc((size_t)T * 2048 * 4);
  unsigned short* h_bf = (unsigned short*)alloc((size_t)T * 2048 * 2);
  float* x2 = (float*)alloc((size_t)T * 2048 * 4);
  unsigned short* h2_bf = (unsigned short*)alloc((size_t)T * 2048 * 2);
  float* cosT = (float*)alloc((size_t)1024 * 64 * 4);
  float* sinT = (float*)alloc((size_t)1024 * 64 * 4);

  // aliases with disjoint lifetimes (stream-ordered):
  unsigned short* ao_bf = h_bf;                  // after h consumed by QKVZ GEMMs
  unsigned short* gu_bf = (unsigned short*)qbuf; // after attention consumed q/k/v/z
  // q_bf/k_bf/vt live inside x2 (x2 written only after attention, by Wo GEMM)
  char* x2c = (char*)x2;
  unsigned short* vt_bf = (unsigned short*)(x2c);                    // 4.19 MB
  unsigned short* k_bf  = (unsigned short*)(x2c + 4194304);          // 4.19 MB
  unsigned short* q_bf  = (unsigned short*)(x2c + 8388608);          // 16.8 MB

  auto cvt = [&](const float* s, unsigned short* d, size_t n) {
    int n4 = (int)(n / 4);
    int blocks = (n4 + 255) / 256;
    if (blocks > 2048) blocks = 2048;
    k_f32_to_bf16<<<blocks, 256, 0, stream>>>(s, d, n4);
  };
  cvt(Wq, Wq_b, (size_t)2048 * 2048);
  cvt(Wk, Wk_b, (size_t)512 * 2048);
  cvt(Wv, Wv_b, (size_t)512 * 2048);
  cvt(Wz, Wz_b, (size_t)2048 * 2048);
  cvt(Wo, Wo_b, (size_t)2048 * 2048);
  cvt(Wg, Wg_b, (size_t)8192 * 2048);
  cvt(Wu, Wu_b, (size_t)8192 * 2048);
  cvt(Wd, Wd_b, (size_t)2048 * 8192);

  k_rope_table<<<256, 256, 0, stream>>>(cosT, sinT);

  // h = rmsnorm(x, in_ln)
  k_rmsnorm<<<T, 256, 0, stream>>>(x, in_ln, h_bf);

  // QKVZ projections (f32 out for q/k/v/z)
  k_gemm_bt<0><<<dim3(16, 32), 256, 0, stream>>>(h_bf, Wq_b, nullptr, qbuf, nullptr, nullptr, T, 2048, 2048);
  k_gemm_bt<0><<<dim3(4, 32), 256, 0, stream>>>(h_bf, Wk_b, nullptr, kbuf, nullptr, nullptr, T, 512, 2048);
  k_gemm_bt<0><<<dim3(4, 32), 256, 0, stream>>>(h_bf, Wv_b, nullptr, vbuf, nullptr, nullptr, T, 512, 2048);
  k_gemm_bt<0><<<dim3(16, 32), 256, 0, stream>>>(h_bf, Wz_b, nullptr, zbuf, nullptr, nullptr, T, 2048, 2048);

  // per-head q/k RMSNorm + RoPE -> bf16
  k_qknorm_rope<<<20480, 256, 0, stream>>>(qbuf, kbuf, q_bf, k_bf, qn_w, kn_w, cosT, sinT);

  // V -> V^T bf16 per (b,kv)
  k_transpose_v<<<dim3(16, 4, 4), 256, 0, stream>>>(vbuf, vt_bf);

  // causal GQA attention (MFMA) + sigmoid(z) gate -> ao_bf
  k_attn_mfma<<<dim3(16, 16, 4), 256, 0, stream>>>(q_bf, k_bf, vt_bf, zbuf, ao_bf);

  // x2 = x + ao @ Wo^T
  k_gemm_bt<1><<<dim3(16, 32), 256, 0, stream>>>(ao_bf, Wo_b, nullptr, x2, nullptr, x, T, 2048, 2048);

  // h2 = rmsnorm(x2, post_ln)
  k_rmsnorm<<<T, 256, 0, stream>>>(x2, post_ln, h2_bf);

  // gu = silu(h2 @ Wg^T) * (h2 @ Wu^T)   (bf16)
  k_gemm_bt<2><<<dim3(64, 32), 256, 0, stream>>>(h2_bf, Wg_b, Wu_b, nullptr, gu_bf, nullptr, T, 8192, 2048);

  // out = x2 + gu @ Wd^T
  k_gemm_bt<1><<<dim3(16, 32), 256, 0, stream>>>(gu_bf, Wd_b, nullptr, (float*)d_out, nullptr, x2, T, 2048, 8192);
}

// Round 4
// 1056.859 us; speedup vs baseline: 1.7510x; 1.2615x over previous
//
#include <hip/hip_runtime.h>

// ---------------------------------------------------------------------------
// DecoderLayer on MI355X: rmsnorm -> fused QKVZ proj (bf16 out) -> qk-norm+rope
// -> causal GQA attention (sigmoid-gated, bf16 MFMA flash) -> Wo + residual ->
// rmsnorm -> SwiGLU MLP (split GEMMs, in-place silu-combine) + residual.
// GEMMs: bf16 MFMA 16x16x32, 128x128 tiles, global_load_lds staging, XCD swizzle.
// Workspace budget ~236 MB (known-good cap is >268 MB; round-3's 332 MB aborted).
// ---------------------------------------------------------------------------

typedef __attribute__((ext_vector_type(4))) float  f32x4;
typedef __attribute__((ext_vector_type(8))) short  s16x8;
typedef __attribute__((ext_vector_type(4))) unsigned short u16x4;

#define DEVI static __device__ __forceinline__

DEVI unsigned short f2bf(float f) {
  union { float f; unsigned u; } a; a.f = f;
  unsigned r = a.u + 0x7FFFu + ((a.u >> 16) & 1u);   // round-to-nearest-even
  return (unsigned short)(r >> 16);
}
DEVI float bf2f(unsigned short u) {
  union { unsigned u; float f; } a; a.u = (unsigned)u << 16; return a.f;
}

// global -> LDS async copy, 16B per lane. LDS dest is wave-uniform base + lane*16.
DEVI void gload16(const void* g, void* l) {
  __builtin_amdgcn_global_load_lds(
      (const __attribute__((address_space(1))) unsigned int*)(unsigned long long)g,
      (__attribute__((address_space(3))) unsigned int*)(unsigned int)(unsigned long long)l,
      16, 0, 0);
}

// ---------------------------------------------------------------------------
// f32 -> bf16 conversion (vectorized)
// ---------------------------------------------------------------------------
__global__ void k_f32_to_bf16(const float* __restrict__ src,
                              unsigned short* __restrict__ dst, int n4) {
  int i = blockIdx.x * blockDim.x + threadIdx.x;
  int stride = gridDim.x * blockDim.x;
  for (; i < n4; i += stride) {
    f32x4 v = ((const f32x4*)src)[i];
    u16x4 o;
    o.x = f2bf(v.x); o.y = f2bf(v.y); o.z = f2bf(v.z); o.w = f2bf(v.w);
    ((u16x4*)dst)[i] = o;
  }
}

// ---------------------------------------------------------------------------
// Row RMSNorm over H=2048 (f32 in, bf16 out)
// ---------------------------------------------------------------------------
__global__ __launch_bounds__(256) void k_rmsnorm(const float* __restrict__ x,
                                                 const float* __restrict__ w,
                                                 unsigned short* __restrict__ out) {
  const int row = blockIdx.x, t = threadIdx.x;
  const f32x4* xr = (const f32x4*)(x + (size_t)row * 2048);
  f32x4 a = xr[t * 2], b = xr[t * 2 + 1];
  float ss = a.x*a.x + a.y*a.y + a.z*a.z + a.w*a.w
           + b.x*b.x + b.y*b.y + b.z*b.z + b.w*b.w;
#pragma unroll
  for (int m = 32; m; m >>= 1) ss += __shfl_xor(ss, m);
  __shared__ float sred[4];
  if ((t & 63) == 0) sred[t >> 6] = ss;
  __syncthreads();
  float tot = sred[0] + sred[1] + sred[2] + sred[3];
  float r = rsqrtf(tot * (1.0f / 2048.0f) + 1e-6f);
  const f32x4* wr = (const f32x4*)w;
  f32x4 w1 = wr[t * 2], w2 = wr[t * 2 + 1];
  u16x4 o1, o2;
  o1.x = f2bf(a.x * r * (1.f + w1.x)); o1.y = f2bf(a.y * r * (1.f + w1.y));
  o1.z = f2bf(a.z * r * (1.f + w1.z)); o1.w = f2bf(a.w * r * (1.f + w1.w));
  o2.x = f2bf(b.x * r * (1.f + w2.x)); o2.y = f2bf(b.y * r * (1.f + w2.y));
  o2.z = f2bf(b.z * r * (1.f + w2.z)); o2.w = f2bf(b.w * r * (1.f + w2.w));
  u16x4* od = (u16x4*)(out + (size_t)row * 2048);
  od[t * 2] = o1; od[t * 2 + 1] = o2;
}

// ---------------------------------------------------------------------------
// RoPE cos/sin table: [1024][64] each
// ---------------------------------------------------------------------------
__global__ void k_rope_table(float* __restrict__ cosT, float* __restrict__ sinT) {
  int i = blockIdx.x * blockDim.x + threadIdx.x;   // 65536
  int tpos = i >> 6, f = i & 63;
  double inv = exp(-0.14391156831212787 * (double)f);  // ln(10000)/64
  float ang = (float)tpos * (float)inv;
  cosT[i] = cosf(ang);
  sinT[i] = sinf(ang);
}

// ---------------------------------------------------------------------------
// Per-head RMSNorm (HD=128) + RoPE, reading from fused QKVZ buffer
// [4096][5120] bf16 (q at col 0, k at col 2048). bf16 out.
// One wave per (token, head). 20 heads per token (16 q + 4 k).
// ---------------------------------------------------------------------------
__global__ __launch_bounds__(256) void k_qknorm_rope(
    const unsigned short* __restrict__ QKVZ,
    unsigned short* __restrict__ Qo, unsigned short* __restrict__ Ko,
    const float* __restrict__ qw, const float* __restrict__ kw,
    const float* __restrict__ cosT, const float* __restrict__ sinT) {
  int gid = blockIdx.x * 4 + (threadIdx.x >> 6);
  int lane = threadIdx.x & 63;
  int tok = gid / 20, hh = gid % 20;
  const unsigned short* p; const float* w; unsigned short* o;
  if (hh < 16) { p = QKVZ + (size_t)tok * 5120 + hh * 128; w = qw;
                 o = Qo + (size_t)tok * 2048 + hh * 128; }
  else         { p = QKVZ + (size_t)tok * 5120 + 2048 + (hh - 16) * 128; w = kw;
                 o = Ko + (size_t)tok * 512 + (hh - 16) * 128; }
  float x1 = bf2f(p[lane]), x2 = bf2f(p[lane + 64]);
  float ss = x1 * x1 + x2 * x2;
#pragma unroll
  for (int m = 1; m < 64; m <<= 1) ss += __shfl_xor(ss, m);
  float r = rsqrtf(ss * (1.0f / 128.0f) + 1e-6f);
  float n1 = x1 * r * (1.f + w[lane]);
  float n2 = x2 * r * (1.f + w[lane + 64]);
  int s = tok & 1023;
  float c = cosT[s * 64 + lane], sn = sinT[s * 64 + lane];
  o[lane]      = f2bf(n1 * c - n2 * sn);
  o[lane + 64] = f2bf(n2 * c + n1 * sn);
}

// ---------------------------------------------------------------------------
// V transpose: QKVZ bf16 [4096][5120] (v at col 2560) -> Vt bf16
// [(b*4+kv)][128 d][1024 key]
// ---------------------------------------------------------------------------
__global__ __launch_bounds__(256) void k_transpose_v(const unsigned short* __restrict__ QKVZ,
                                                     unsigned short* __restrict__ Vt) {
  __shared__ unsigned short Vl[128 * 66];
  const int t = threadIdx.x;
  const int key0 = blockIdx.x * 64, kvh = blockIdx.y, b = blockIdx.z;
#pragma unroll
  for (int i = 0; i < 4; ++i) {
    int g = i * 256 + t;                 // 1024 granules of 8 bf16
    int key = g >> 4, dc = (g & 15) * 8;
    s16x8 v = *(const s16x8*)&QKVZ[(size_t)(b * 1024 + key0 + key) * 5120 + 2560 + kvh * 128 + dc];
#pragma unroll
    for (int j = 0; j < 8; ++j) Vl[(dc + j) * 66 + key] = (unsigned short)v[j];
  }
  __syncthreads();
#pragma unroll
  for (int i = 0; i < 8; ++i) {
    int g = i * 256 + t;                 // 2048 u16x4 granules
    int d = g >> 4, kc = g & 15;
    u16x4 o;
#pragma unroll
    for (int j = 0; j < 4; ++j) o[j] = Vl[d * 66 + kc * 4 + j];
    *(u16x4*)&Vt[((size_t)(b * 4 + kvh) * 128 + d) * 1024 + key0 + kc * 4] = o;
  }
}

// ---------------------------------------------------------------------------
// GEMM  C[M,N] = A[M,K] (bf16) . B[N,K]^T (bf16), f32 accumulate via MFMA.
// EPI 0: store f32.       EPI 1: f32 + residual (f32).
// EPI 2: store bf16.      EPI 4: in-place bf16( silu(Cb[idx]) * acc ).
// 128x128 tile, BK=32, 4 waves 2x2, 4x4 frags. Bijective XCD blockIdx swizzle.
// ---------------------------------------------------------------------------
template <int EPI>
__global__ __launch_bounds__(256) void k_gemm_bt(
    const unsigned short* __restrict__ A, const unsigned short* __restrict__ B,
    float* __restrict__ Cf, unsigned short* __restrict__ Cb,
    const float* __restrict__ res,
    int M, int N, int K) {
  __shared__ unsigned short As[128 * 32];
  __shared__ unsigned short Bs[128 * 32];

  const int t = threadIdx.x, lane = t & 63, w = t >> 6;
  const int wr = w >> 1, wc = w & 1;
  // XCD-aware bijective swizzle (nwg % 8 == 0 for all our grids)
  const int nbx = gridDim.x;
  const int nwg = nbx * gridDim.y;
  const int bid = blockIdx.y * nbx + blockIdx.x;
  const int sw = (bid & 7) * (nwg >> 3) + (bid >> 3);
  const int m0 = (sw / nbx) * 128, n0 = (sw % nbx) * 128;

  f32x4 acc[4][4] = {};

  const int srow = lane >> 2;
  const int scol = (lane & 3) * 8;

  for (int kk = 0; kk < K; kk += 32) {
#pragma unroll
    for (int r = 0; r < 2; ++r) {
      int row = 16 * w + srow + 64 * r;
      gload16(A + (size_t)(m0 + row) * K + kk + scol, (void*)&As[w * 512 + r * 2048]);
      gload16(B + (size_t)(n0 + row) * K + kk + scol, (void*)&Bs[w * 512 + r * 2048]);
    }
    __syncthreads();

    s16x8 af[4], bf_[4];
#pragma unroll
    for (int i = 0; i < 4; ++i) {
      af[i]  = *(const s16x8*)&As[(wr * 64 + i * 16 + (lane & 15)) * 32 + (lane >> 4) * 8];
      bf_[i] = *(const s16x8*)&Bs[(wc * 64 + i * 16 + (lane & 15)) * 32 + (lane >> 4) * 8];
    }
#pragma unroll
    for (int mi = 0; mi < 4; ++mi)
#pragma unroll
      for (int ni = 0; ni < 4; ++ni)
        acc[mi][ni] = __builtin_amdgcn_mfma_f32_16x16x32_bf16(af[mi], bf_[ni], acc[mi][ni], 0, 0, 0);
    __syncthreads();
  }

  const int er = (lane >> 4) * 4;
  const int ec = lane & 15;
#pragma unroll
  for (int mi = 0; mi < 4; ++mi)
#pragma unroll
    for (int ni = 0; ni < 4; ++ni) {
      int col = n0 + wc * 64 + ni * 16 + ec;
#pragma unroll
      for (int j = 0; j < 4; ++j) {
        int row = m0 + wr * 64 + mi * 16 + er + j;
        size_t idx = (size_t)row * N + col;
        float g = acc[mi][ni][j];
        if constexpr (EPI == 0) {
          Cf[idx] = g;
        } else if constexpr (EPI == 1) {
          Cf[idx] = g + res[idx];
        } else if constexpr (EPI == 2) {
          Cb[idx] = f2bf(g);
        } else {
          float gv = bf2f(Cb[idx]);              // previous GEMM's g (in place)
          float sg = gv / (1.f + __expf(-gv));   // silu
          Cb[idx] = f2bf(sg * g);
        }
      }
    }
}

// ---------------------------------------------------------------------------
// Causal GQA attention, bf16 MFMA flash. Block = 64 q-rows of one (b,h),
// 4 waves x 16 q-rows. Q frags persistent in regs; K [64x128] and V^T [128x64]
// staged via global_load_lds with XOR-granule swizzle (conflict-free ds_read_b128).
// Online softmax in registers; P via per-wave swizzled LDS. Epilogue fuses
// sigmoid(z) gate (z read bf16 from fused QKVZ buffer), writes bf16.
// ---------------------------------------------------------------------------
__global__ __launch_bounds__(256) void k_attn_mfma(
    const unsigned short* __restrict__ Qb,   // [4096][2048] bf16
    const unsigned short* __restrict__ Kb,   // [4096][512]  bf16
    const unsigned short* __restrict__ Vt,   // [16][128][1024] bf16
    const unsigned short* __restrict__ Zb,   // [4096][5120] bf16, pre-offset to z col 0
    unsigned short* __restrict__ AO) {       // [4096][2048] bf16
  __shared__ unsigned short Qs[64 * 128];
  __shared__ unsigned short Ks[64 * 128];
  __shared__ unsigned short Vts[128 * 64];
  __shared__ unsigned short Ps[4][16 * 64];

  const int t = threadIdx.x, lane = t & 63, w = t >> 6;
  const int l15 = lane & 15, l4 = lane >> 4;
  const int qt = (int)gridDim.x - 1 - (int)blockIdx.x;   // long blocks first
  const int qs0 = qt * 64;
  const int h = blockIdx.y, b = blockIdx.z;
  const int kv = h >> 2;

  // ---- stage Q tile (64 x 128) with granule swizzle c' = (c&8)|((c&7)^(row&7))
  {
    const unsigned short* qb = Qb + (size_t)(b * 1024 + qs0) * 2048 + h * 128;
#pragma unroll
    for (int r = 0; r < 4; ++r) {
      int row = r * 16 + w * 4 + (lane >> 4);
      int cp = lane & 15;
      int c = (cp & 8) | ((cp & 7) ^ (row & 7));
      gload16(qb + (size_t)row * 2048 + c * 8, (void*)&Qs[(r * 256 + w * 64) * 8]);
    }
  }

  auto stageKV = [&](int j0) {
    const unsigned short* kb = Kb + (size_t)(b * 1024 + j0) * 512 + kv * 128;
#pragma unroll
    for (int r = 0; r < 4; ++r) {
      int row = r * 16 + w * 4 + (lane >> 4);
      int cp = lane & 15;
      int c = (cp & 8) | ((cp & 7) ^ (row & 7));
      gload16(kb + (size_t)row * 512 + c * 8, (void*)&Ks[(r * 256 + w * 64) * 8]);
    }
    const unsigned short* vb = Vt + (size_t)(b * 4 + kv) * 131072 + j0;
#pragma unroll
    for (int r = 0; r < 4; ++r) {
      int row = r * 32 + w * 8 + (lane >> 3);
      int cp = lane & 7;
      int c = cp ^ (row & 7);
      gload16(vb + (size_t)row * 1024 + c * 8, (void*)&Vts[(r * 256 + w * 64) * 8]);
    }
  };

  stageKV(0);
  __syncthreads();   // compiler drains vmcnt before barrier -> Qs/Ks/Vts valid

  // persistent Q fragments: A-row = l15 (q within wave tile), k = l4*8 + ks*32
  s16x8 qf[4];
#pragma unroll
  for (int ks = 0; ks < 4; ++ks) {
    int R = w * 16 + l15;
    int c = ks * 4 + l4;
    int cp = (c & 8) | ((c & 7) ^ (R & 7));
    qf[ks] = *(const s16x8*)&Qs[R * 128 + cp * 8];
  }

  f32x4 O[8] = {};
  f32x4 mrow = {-1e30f, -1e30f, -1e30f, -1e30f};
  f32x4 lrow = {0.f, 0.f, 0.f, 0.f};
  const float scale = 0.088388347648318447f;   // 1/sqrt(128)

  for (int tile = 0; tile <= qt; ++tile) {
    // ---- S = Q . K^T  (C layout: col=key=kt*16+l15, row=q=l4*4+reg)
    f32x4 sc[4] = {};
#pragma unroll
    for (int ks = 0; ks < 4; ++ks) {
#pragma unroll
      for (int kt = 0; kt < 4; ++kt) {
        int R = kt * 16 + l15;
        int c = ks * 4 + l4;
        int cp = (c & 8) | ((c & 7) ^ (R & 7));
        s16x8 kf = *(const s16x8*)&Ks[R * 128 + cp * 8];
        sc[kt] = __builtin_amdgcn_mfma_f32_16x16x32_bf16(qf[ks], kf, sc[kt], 0, 0, 0);
      }
    }
    // ---- mask + scale
    const bool diag = (tile == qt);
#pragma unroll
    for (int kt = 0; kt < 4; ++kt) {
      int key = kt * 16 + l15;
#pragma unroll
      for (int j = 0; j < 4; ++j) {
        float s = sc[kt][j] * scale;
        if (diag && key > (w * 16 + l4 * 4 + j)) s = -1e30f;
        sc[kt][j] = s;
      }
    }
    // ---- online softmax (row = q, reduce across the 16-lane key group)
    f32x4 mt;
#pragma unroll
    for (int j = 0; j < 4; ++j)
      mt[j] = fmaxf(fmaxf(sc[0][j], sc[1][j]), fmaxf(sc[2][j], sc[3][j]));
#pragma unroll
    for (int msk = 1; msk < 16; msk <<= 1)
#pragma unroll
      for (int j = 0; j < 4; ++j) mt[j] = fmaxf(mt[j], __shfl_xor(mt[j], msk));
    f32x4 mnew, rs;
#pragma unroll
    for (int j = 0; j < 4; ++j) {
      mnew[j] = fmaxf(mrow[j], mt[j]);
      rs[j] = __expf(mrow[j] - mnew[j]);
    }
    f32x4 psum = {0.f, 0.f, 0.f, 0.f};
    unsigned short* pw = &Ps[w][0];
#pragma unroll
    for (int kt = 0; kt < 4; ++kt) {
      int kg = kt * 2 + (l15 >> 3), ke = l15 & 7;
#pragma unroll
      for (int j = 0; j < 4; ++j) {
        float p = __expf(sc[kt][j] - mnew[j]);
        psum[j] += p;
        int q = l4 * 4 + j;
        pw[q * 64 + ((kg ^ (q & 7)) * 8) + ke] = f2bf(p);
      }
    }
#pragma unroll
    for (int msk = 1; msk < 16; msk <<= 1)
#pragma unroll
      for (int j = 0; j < 4; ++j) psum[j] += __shfl_xor(psum[j], msk);
    mrow = mnew;
#pragma unroll
    for (int j = 0; j < 4; ++j) lrow[j] = lrow[j] * rs[j] + psum[j];
#pragma unroll
    for (int dt = 0; dt < 8; ++dt) O[dt] *= rs;
    // ---- O += P . V  (A = P rows q, B = V^T rows d; contraction over keys)
#pragma unroll
    for (int js = 0; js < 2; ++js) {
      int cpp = (js * 4 + l4) ^ (l15 & 7);
      s16x8 pf = *(const s16x8*)&Ps[w][l15 * 64 + cpp * 8];
#pragma unroll
      for (int dt = 0; dt < 8; ++dt) {
        int D = dt * 16 + l15;
        s16x8 vf = *(const s16x8*)&Vts[D * 64 + cpp * 8];   // D&7 == l15&7
        O[dt] = __builtin_amdgcn_mfma_f32_16x16x32_bf16(pf, vf, O[dt], 0, 0, 0);
      }
    }
    __syncthreads();                       // all waves done with Ks/Vts
    if (tile < qt) stageKV((tile + 1) * 64);
    __syncthreads();                       // staged tile visible
  }

  // ---- epilogue: normalize, sigmoid(z) gate, bf16 store
  f32x4 linv;
#pragma unroll
  for (int j = 0; j < 4; ++j) linv[j] = 1.f / lrow[j];
  const int tok0 = b * 1024 + qs0 + w * 16 + l4 * 4;
#pragma unroll
  for (int dt = 0; dt < 8; ++dt) {
    int d = dt * 16 + l15;
#pragma unroll
    for (int j = 0; j < 4; ++j) {
      size_t zidx = (size_t)(tok0 + j) * 5120 + h * 128 + d;
      size_t aidx = (size_t)(tok0 + j) * 2048 + h * 128 + d;
      float z = bf2f(Zb[zidx]);
      float o = O[dt][j] * linv[j];
      AO[aidx] = f2bf(o / (1.f + __expf(-z)));
    }
  }
}

// ---------------------------------------------------------------------------
// launcher
// ---------------------------------------------------------------------------
extern "C" void kernel_launch(void* const* d_in, const int* in_sizes, int n_in,
                              void* d_out, int out_size, void* d_ws, size_t ws_size,
                              hipStream_t stream) {
  const float* x       = (const float*)d_in[0];
  const float* in_ln   = (const float*)d_in[1];
  const float* Wq      = (const float*)d_in[2];
  const float* Wk      = (const float*)d_in[3];
  const float* Wv      = (const float*)d_in[4];
  const float* Wz      = (const float*)d_in[5];
  const float* Wo      = (const float*)d_in[6];
  const float* qn_w    = (const float*)d_in[7];
  const float* kn_w    = (const float*)d_in[8];
  const float* post_ln = (const float*)d_in[9];
  const float* Wg      = (const float*)d_in[10];
  const float* Wu      = (const float*)d_in[11];
  const float* Wd      = (const float*)d_in[12];

  const int T = 4096;   // B*S tokens

  char* ws = (char*)d_ws;
  size_t off = 0;
  auto alloc = [&](size_t bytes) -> void* {
    off = (off + 255) & ~(size_t)255;
    void* p = ws + off;
    off += bytes;
    return p;
  };

  // --- weights (regenerated by cvt every launch; individually dead after use)
  // fused QKVZ weight: rows 0-2047 Wq, 2048-2559 Wk, 2560-3071 Wv, 3072-5119 Wz
  unsigned short* Wqkvz_b = (unsigned short*)alloc((size_t)5120 * 2048 * 2);  // 20 MB
  unsigned short* Wo_b = (unsigned short*)alloc((size_t)2048 * 2048 * 2);     // 8 MB
  unsigned short* Wg_b = (unsigned short*)alloc((size_t)8192 * 2048 * 2);     // 32 MB
  unsigned short* Wu_b = (unsigned short*)alloc((size_t)8192 * 2048 * 2);     // 32 MB
  unsigned short* Wd_b = (unsigned short*)alloc((size_t)2048 * 8192 * 2);     // 32 MB

  // --- region R: 64 MB. Holds qkvz_bf (40 MB) + h_bf (16 MB) early; the whole
  // 64 MB is reused as gpre/gu (in-place silu-combine) once attention+Wo done.
  char* R = (char*)alloc((size_t)64 * 1024 * 1024);
  unsigned short* qkvz_bf = (unsigned short*)R;                       // 40 MB
  unsigned short* h_bf    = (unsigned short*)(R + (size_t)40 * 1024 * 1024); // 16 MB
  unsigned short* gu_bf   = (unsigned short*)R;                       // 64 MB (later)
  unsigned short* ao_bf   = h_bf;   // attention output (after h consumed)

  // --- x2 (f32, live to the end). Before Wo writes it, its space holds the
  // attention temps q_bf/k_bf/vt_bf (dead once attention completes).
  float* x2 = (float*)alloc((size_t)T * 2048 * 4);                    // 32 MB
  char* x2c = (char*)x2;
  unsigned short* vt_bf = (unsigned short*)(x2c);                     // 4 MB
  unsigned short* k_bf  = (unsigned short*)(x2c + 4194304);           // 4 MB
  unsigned short* q_bf  = (unsigned short*)(x2c + 8388608);           // 16 MB

  unsigned short* h2_bf = (unsigned short*)alloc((size_t)T * 2048 * 2); // 16 MB
  float* cosT = (float*)alloc((size_t)1024 * 64 * 4);
  float* sinT = (float*)alloc((size_t)1024 * 64 * 4);
  // total ~236.5 MB

  auto cvt = [&](const float* s, unsigned short* d, size_t n) {
    int n4 = (int)(n / 4);
    int blocks = (n4 + 255) / 256;
    if (blocks > 2048) blocks = 2048;
    k_f32_to_bf16<<<blocks, 256, 0, stream>>>(s, d, n4);
  };
  cvt(Wq, Wqkvz_b, (size_t)2048 * 2048);
  cvt(Wk, Wqkvz_b + (size_t)2048 * 2048, (size_t)512 * 2048);
  cvt(Wv, Wqkvz_b + (size_t)2560 * 2048, (size_t)512 * 2048);
  cvt(Wz, Wqkvz_b + (size_t)3072 * 2048, (size_t)2048 * 2048);
  cvt(Wo, Wo_b, (size_t)2048 * 2048);
  cvt(Wg, Wg_b, (size_t)8192 * 2048);
  cvt(Wu, Wu_b, (size_t)8192 * 2048);
  cvt(Wd, Wd_b, (size_t)2048 * 8192);

  k_rope_table<<<256, 256, 0, stream>>>(cosT, sinT);

  // h = rmsnorm(x, in_ln)
  k_rmsnorm<<<T, 256, 0, stream>>>(x, in_ln, h_bf);

  // fused QKVZ projection: [4096][5120] bf16
  k_gemm_bt<2><<<dim3(40, 32), 256, 0, stream>>>(h_bf, Wqkvz_b, nullptr, qkvz_bf, nullptr, T, 5120, 2048);

  // per-head q/k RMSNorm + RoPE -> bf16
  k_qknorm_rope<<<20480, 256, 0, stream>>>(qkvz_bf, q_bf, k_bf, qn_w, kn_w, cosT, sinT);

  // V -> V^T bf16 per (b,kv)
  k_transpose_v<<<dim3(16, 4, 4), 256, 0, stream>>>(qkvz_bf, vt_bf);

  // causal GQA attention (MFMA) + sigmoid(z) gate -> ao_bf
  k_attn_mfma<<<dim3(16, 16, 4), 256, 0, stream>>>(q_bf, k_bf, vt_bf, qkvz_bf + 3072, ao_bf);

  // x2 = x + ao @ Wo^T   (overwrites q/k/vt space — dead now)
  k_gemm_bt<1><<<dim3(16, 32), 256, 0, stream>>>(ao_bf, Wo_b, x2, nullptr, x, T, 2048, 2048);

  // h2 = rmsnorm(x2, post_ln)
  k_rmsnorm<<<T, 256, 0, stream>>>(x2, post_ln, h2_bf);

  // gu = h2 @ Wg^T  (bf16; overwrites qkvz/h region — dead now)
  k_gemm_bt<2><<<dim3(64, 32), 256, 0, stream>>>(h2_bf, Wg_b, nullptr, gu_bf, nullptr, T, 8192, 2048);

  // gu = silu(gu) * (h2 @ Wu^T)   (in place)
  k_gemm_bt<4><<<dim3(64, 32), 256, 0, stream>>>(h2_bf, Wu_b, nullptr, gu_bf, nullptr, T, 8192, 2048);

  // out = x2 + gu @ Wd^T
  k_gemm_bt<1><<<dim3(16, 32), 256, 0, stream>>>(gu_bf, Wd_b, (float*)d_out, nullptr, x2, T, 2048, 8192);
}

// Round 5
// 910.534 us; speedup vs baseline: 2.0324x; 1.1607x over previous
//
#include <hip/hip_runtime.h>

// ---------------------------------------------------------------------------
// DecoderLayer on MI355X: rmsnorm -> fused QKVZ proj (bf16 out) -> qk-norm+rope
// -> causal GQA attention (sigmoid-gated, bf16 MFMA flash) -> Wo + residual ->
// rmsnorm -> SwiGLU MLP (split GEMMs, in-place silu-combine) + residual.
// GEMMs: bf16 MFMA 16x16x32, 128x128 tiles, double-buffered global_load_lds
// staging (2-phase pipeline), XCD-chunked + GM=8 supertile rasterization.
// ---------------------------------------------------------------------------

typedef __attribute__((ext_vector_type(4))) float  f32x4;
typedef __attribute__((ext_vector_type(8))) short  s16x8;
typedef __attribute__((ext_vector_type(4))) unsigned short u16x4;

#define DEVI static __device__ __forceinline__

DEVI unsigned short f2bf(float f) {
  union { float f; unsigned u; } a; a.f = f;
  unsigned r = a.u + 0x7FFFu + ((a.u >> 16) & 1u);   // round-to-nearest-even
  return (unsigned short)(r >> 16);
}
DEVI float bf2f(unsigned short u) {
  union { unsigned u; float f; } a; a.u = (unsigned)u << 16; return a.f;
}

// global -> LDS async copy, 16B per lane. LDS dest is wave-uniform base + lane*16.
DEVI void gload16(const void* g, void* l) {
  __builtin_amdgcn_global_load_lds(
      (const __attribute__((address_space(1))) unsigned int*)(unsigned long long)g,
      (__attribute__((address_space(3))) unsigned int*)(unsigned int)(unsigned long long)l,
      16, 0, 0);
}

// ---------------------------------------------------------------------------
// f32 -> bf16 conversion (vectorized)
// ---------------------------------------------------------------------------
__global__ void k_f32_to_bf16(const float* __restrict__ src,
                              unsigned short* __restrict__ dst, int n4) {
  int i = blockIdx.x * blockDim.x + threadIdx.x;
  int stride = gridDim.x * blockDim.x;
  for (; i < n4; i += stride) {
    f32x4 v = ((const f32x4*)src)[i];
    u16x4 o;
    o.x = f2bf(v.x); o.y = f2bf(v.y); o.z = f2bf(v.z); o.w = f2bf(v.w);
    ((u16x4*)dst)[i] = o;
  }
}

// ---------------------------------------------------------------------------
// Row RMSNorm over H=2048 (f32 in, bf16 out)
// ---------------------------------------------------------------------------
__global__ __launch_bounds__(256) void k_rmsnorm(const float* __restrict__ x,
                                                 const float* __restrict__ w,
                                                 unsigned short* __restrict__ out) {
  const int row = blockIdx.x, t = threadIdx.x;
  const f32x4* xr = (const f32x4*)(x + (size_t)row * 2048);
  f32x4 a = xr[t * 2], b = xr[t * 2 + 1];
  float ss = a.x*a.x + a.y*a.y + a.z*a.z + a.w*a.w
           + b.x*b.x + b.y*b.y + b.z*b.z + b.w*b.w;
#pragma unroll
  for (int m = 32; m; m >>= 1) ss += __shfl_xor(ss, m);
  __shared__ float sred[4];
  if ((t & 63) == 0) sred[t >> 6] = ss;
  __syncthreads();
  float tot = sred[0] + sred[1] + sred[2] + sred[3];
  float r = rsqrtf(tot * (1.0f / 2048.0f) + 1e-6f);
  const f32x4* wr = (const f32x4*)w;
  f32x4 w1 = wr[t * 2], w2 = wr[t * 2 + 1];
  u16x4 o1, o2;
  o1.x = f2bf(a.x * r * (1.f + w1.x)); o1.y = f2bf(a.y * r * (1.f + w1.y));
  o1.z = f2bf(a.z * r * (1.f + w1.z)); o1.w = f2bf(a.w * r * (1.f + w1.w));
  o2.x = f2bf(b.x * r * (1.f + w2.x)); o2.y = f2bf(b.y * r * (1.f + w2.y));
  o2.z = f2bf(b.z * r * (1.f + w2.z)); o2.w = f2bf(b.w * r * (1.f + w2.w));
  u16x4* od = (u16x4*)(out + (size_t)row * 2048);
  od[t * 2] = o1; od[t * 2 + 1] = o2;
}

// ---------------------------------------------------------------------------
// RoPE cos/sin table: [1024][64] each
// ---------------------------------------------------------------------------
__global__ void k_rope_table(float* __restrict__ cosT, float* __restrict__ sinT) {
  int i = blockIdx.x * blockDim.x + threadIdx.x;   // 65536
  int tpos = i >> 6, f = i & 63;
  double inv = exp(-0.14391156831212787 * (double)f);  // ln(10000)/64
  float ang = (float)tpos * (float)inv;
  cosT[i] = cosf(ang);
  sinT[i] = sinf(ang);
}

// ---------------------------------------------------------------------------
// Per-head RMSNorm (HD=128) + RoPE, reading from fused QKVZ buffer
// [4096][5120] bf16 (q at col 0, k at col 2048). bf16 out.
// ---------------------------------------------------------------------------
__global__ __launch_bounds__(256) void k_qknorm_rope(
    const unsigned short* __restrict__ QKVZ,
    unsigned short* __restrict__ Qo, unsigned short* __restrict__ Ko,
    const float* __restrict__ qw, const float* __restrict__ kw,
    const float* __restrict__ cosT, const float* __restrict__ sinT) {
  int gid = blockIdx.x * 4 + (threadIdx.x >> 6);
  int lane = threadIdx.x & 63;
  int tok = gid / 20, hh = gid % 20;
  const unsigned short* p; const float* w; unsigned short* o;
  if (hh < 16) { p = QKVZ + (size_t)tok * 5120 + hh * 128; w = qw;
                 o = Qo + (size_t)tok * 2048 + hh * 128; }
  else         { p = QKVZ + (size_t)tok * 5120 + 2048 + (hh - 16) * 128; w = kw;
                 o = Ko + (size_t)tok * 512 + (hh - 16) * 128; }
  float x1 = bf2f(p[lane]), x2 = bf2f(p[lane + 64]);
  float ss = x1 * x1 + x2 * x2;
#pragma unroll
  for (int m = 1; m < 64; m <<= 1) ss += __shfl_xor(ss, m);
  float r = rsqrtf(ss * (1.0f / 128.0f) + 1e-6f);
  float n1 = x1 * r * (1.f + w[lane]);
  float n2 = x2 * r * (1.f + w[lane + 64]);
  int s = tok & 1023;
  float c = cosT[s * 64 + lane], sn = sinT[s * 64 + lane];
  o[lane]      = f2bf(n1 * c - n2 * sn);
  o[lane + 64] = f2bf(n2 * c + n1 * sn);
}

// ---------------------------------------------------------------------------
// V transpose: QKVZ bf16 [4096][5120] (v at col 2560) -> Vt bf16
// [(b*4+kv)][128 d][1024 key]
// ---------------------------------------------------------------------------
__global__ __launch_bounds__(256) void k_transpose_v(const unsigned short* __restrict__ QKVZ,
                                                     unsigned short* __restrict__ Vt) {
  __shared__ unsigned short Vl[128 * 66];
  const int t = threadIdx.x;
  const int key0 = blockIdx.x * 64, kvh = blockIdx.y, b = blockIdx.z;
#pragma unroll
  for (int i = 0; i < 4; ++i) {
    int g = i * 256 + t;                 // 1024 granules of 8 bf16
    int key = g >> 4, dc = (g & 15) * 8;
    s16x8 v = *(const s16x8*)&QKVZ[(size_t)(b * 1024 + key0 + key) * 5120 + 2560 + kvh * 128 + dc];
#pragma unroll
    for (int j = 0; j < 8; ++j) Vl[(dc + j) * 66 + key] = (unsigned short)v[j];
  }
  __syncthreads();
#pragma unroll
  for (int i = 0; i < 8; ++i) {
    int g = i * 256 + t;                 // 2048 u16x4 granules
    int d = g >> 4, kc = g & 15;
    u16x4 o;
#pragma unroll
    for (int j = 0; j < 4; ++j) o[j] = Vl[d * 66 + kc * 4 + j];
    *(u16x4*)&Vt[((size_t)(b * 4 + kvh) * 128 + d) * 1024 + key0 + kc * 4] = o;
  }
}

// ---------------------------------------------------------------------------
// GEMM  C[M,N] = A[M,K] (bf16) . B[N,K]^T (bf16), f32 accumulate via MFMA.
// EPI 0: store f32.       EPI 1: f32 + residual (f32).
// EPI 2: store bf16.      EPI 4: in-place bf16( silu(Cb[idx]) * acc ).
// 128x128 tile, BK=32, 4 waves 2x2, 4x4 frags. Double-buffered LDS 2-phase
// pipeline. Rasterization: XCD-contiguous chunks + GM=8 supertiles (B-panel
// reused 8x in L2; A-group working set 4MB).
// ---------------------------------------------------------------------------
template <int EPI>
__global__ __launch_bounds__(256) void k_gemm_bt(
    const unsigned short* __restrict__ A, const unsigned short* __restrict__ B,
    float* __restrict__ Cf, unsigned short* __restrict__ Cb,
    const float* __restrict__ res,
    int M, int N, int K) {
  __shared__ unsigned short As[2][128 * 32];
  __shared__ unsigned short Bs[2][128 * 32];

  const int t = threadIdx.x, lane = t & 63, w = t >> 6;
  const int wr = w >> 1, wc = w & 1;
  // XCD-chunked + GM=8 supertile raster (nwg % 8 == 0, gridDim.y % 8 == 0)
  const int nbx = gridDim.x;
  const int nwg = nbx * gridDim.y;
  const int bid = blockIdx.y * nbx + blockIdx.x;
  const int sw = (bid & 7) * (nwg >> 3) + (bid >> 3);
  const int tpg = 8 * nbx;
  const int mi = (sw / tpg) * 8 + (sw & 7);
  const int ni = (sw % tpg) >> 3;
  const int m0 = mi * 128, n0 = ni * 128;

  f32x4 acc[4][4] = {};

  const int srow = lane >> 2;
  const int scol = (lane & 3) * 8;

  auto stage = [&](int kk, int sel) {
#pragma unroll
    for (int r = 0; r < 2; ++r) {
      int row = 16 * w + srow + 64 * r;
      gload16(A + (size_t)(m0 + row) * K + kk + scol, (void*)&As[sel][w * 512 + r * 2048]);
      gload16(B + (size_t)(n0 + row) * K + kk + scol, (void*)&Bs[sel][w * 512 + r * 2048]);
    }
  };

  stage(0, 0);
  __syncthreads();                         // drains vmcnt -> buf0 valid

  const int nk = K >> 5;
  for (int tk = 0; tk < nk; ++tk) {
    const int cur = tk & 1;
    if (tk + 1 < nk) stage((tk + 1) << 5, cur ^ 1);   // overlap with compute

    s16x8 af[4], bf_[4];
#pragma unroll
    for (int i = 0; i < 4; ++i) {
      af[i]  = *(const s16x8*)&As[cur][(wr * 64 + i * 16 + (lane & 15)) * 32 + (lane >> 4) * 8];
      bf_[i] = *(const s16x8*)&Bs[cur][(wc * 64 + i * 16 + (lane & 15)) * 32 + (lane >> 4) * 8];
    }
#pragma unroll
    for (int mi2 = 0; mi2 < 4; ++mi2)
#pragma unroll
      for (int ni2 = 0; ni2 < 4; ++ni2)
        acc[mi2][ni2] = __builtin_amdgcn_mfma_f32_16x16x32_bf16(af[mi2], bf_[ni2], acc[mi2][ni2], 0, 0, 0);
    __syncthreads();   // drains vmcnt(0): next buf staged; syncs readers of cur
  }

  const int er = (lane >> 4) * 4;
  const int ec = lane & 15;
#pragma unroll
  for (int mi2 = 0; mi2 < 4; ++mi2)
#pragma unroll
    for (int ni2 = 0; ni2 < 4; ++ni2) {
      int col = n0 + wc * 64 + ni2 * 16 + ec;
#pragma unroll
      for (int j = 0; j < 4; ++j) {
        int row = m0 + wr * 64 + mi2 * 16 + er + j;
        size_t idx = (size_t)row * N + col;
        float g = acc[mi2][ni2][j];
        if constexpr (EPI == 0) {
          Cf[idx] = g;
        } else if constexpr (EPI == 1) {
          Cf[idx] = g + res[idx];
        } else if constexpr (EPI == 2) {
          Cb[idx] = f2bf(g);
        } else {
          float gv = bf2f(Cb[idx]);              // previous GEMM's g (in place)
          float sg = gv / (1.f + __expf(-gv));   // silu
          Cb[idx] = f2bf(sg * g);
        }
      }
    }
}

// ---------------------------------------------------------------------------
// Causal GQA attention, bf16 MFMA flash. Block = 64 q-rows of one (b,h),
// 4 waves x 16 q-rows. Q frags persistent in regs; K [64x128] and V^T [128x64]
// staged via global_load_lds with XOR-granule swizzle (conflict-free ds_read_b128).
// Online softmax in registers; P via per-wave swizzled LDS. Epilogue fuses
// sigmoid(z) gate (z read bf16 from fused QKVZ buffer), writes bf16.
// ---------------------------------------------------------------------------
__global__ __launch_bounds__(256) void k_attn_mfma(
    const unsigned short* __restrict__ Qb,   // [4096][2048] bf16
    const unsigned short* __restrict__ Kb,   // [4096][512]  bf16
    const unsigned short* __restrict__ Vt,   // [16][128][1024] bf16
    const unsigned short* __restrict__ Zb,   // [4096][5120] bf16, pre-offset to z col 0
    unsigned short* __restrict__ AO) {       // [4096][2048] bf16
  __shared__ unsigned short Qs[64 * 128];
  __shared__ unsigned short Ks[64 * 128];
  __shared__ unsigned short Vts[128 * 64];
  __shared__ unsigned short Ps[4][16 * 64];

  const int t = threadIdx.x, lane = t & 63, w = t >> 6;
  const int l15 = lane & 15, l4 = lane >> 4;
  const int qt = (int)gridDim.x - 1 - (int)blockIdx.x;   // long blocks first
  const int qs0 = qt * 64;
  const int h = blockIdx.y, b = blockIdx.z;
  const int kv = h >> 2;

  // ---- stage Q tile (64 x 128) with granule swizzle c' = (c&8)|((c&7)^(row&7))
  {
    const unsigned short* qb = Qb + (size_t)(b * 1024 + qs0) * 2048 + h * 128;
#pragma unroll
    for (int r = 0; r < 4; ++r) {
      int row = r * 16 + w * 4 + (lane >> 4);
      int cp = lane & 15;
      int c = (cp & 8) | ((cp & 7) ^ (row & 7));
      gload16(qb + (size_t)row * 2048 + c * 8, (void*)&Qs[(r * 256 + w * 64) * 8]);
    }
  }

  auto stageKV = [&](int j0) {
    const unsigned short* kb = Kb + (size_t)(b * 1024 + j0) * 512 + kv * 128;
#pragma unroll
    for (int r = 0; r < 4; ++r) {
      int row = r * 16 + w * 4 + (lane >> 4);
      int cp = lane & 15;
      int c = (cp & 8) | ((cp & 7) ^ (row & 7));
      gload16(kb + (size_t)row * 512 + c * 8, (void*)&Ks[(r * 256 + w * 64) * 8]);
    }
    const unsigned short* vb = Vt + (size_t)(b * 4 + kv) * 131072 + j0;
#pragma unroll
    for (int r = 0; r < 4; ++r) {
      int row = r * 32 + w * 8 + (lane >> 3);
      int cp = lane & 7;
      int c = cp ^ (row & 7);
      gload16(vb + (size_t)row * 1024 + c * 8, (void*)&Vts[(r * 256 + w * 64) * 8]);
    }
  };

  stageKV(0);
  __syncthreads();   // compiler drains vmcnt before barrier -> Qs/Ks/Vts valid

  // persistent Q fragments: A-row = l15 (q within wave tile), k = l4*8 + ks*32
  s16x8 qf[4];
#pragma unroll
  for (int ks = 0; ks < 4; ++ks) {
    int R = w * 16 + l15;
    int c = ks * 4 + l4;
    int cp = (c & 8) | ((c & 7) ^ (R & 7));
    qf[ks] = *(const s16x8*)&Qs[R * 128 + cp * 8];
  }

  f32x4 O[8] = {};
  f32x4 mrow = {-1e30f, -1e30f, -1e30f, -1e30f};
  f32x4 lrow = {0.f, 0.f, 0.f, 0.f};
  const float scale = 0.088388347648318447f;   // 1/sqrt(128)

  for (int tile = 0; tile <= qt; ++tile) {
    // ---- S = Q . K^T  (C layout: col=key=kt*16+l15, row=q=l4*4+reg)
    f32x4 sc[4] = {};
#pragma unroll
    for (int ks = 0; ks < 4; ++ks) {
#pragma unroll
      for (int kt = 0; kt < 4; ++kt) {
        int R = kt * 16 + l15;
        int c = ks * 4 + l4;
        int cp = (c & 8) | ((c & 7) ^ (R & 7));
        s16x8 kf = *(const s16x8*)&Ks[R * 128 + cp * 8];
        sc[kt] = __builtin_amdgcn_mfma_f32_16x16x32_bf16(qf[ks], kf, sc[kt], 0, 0, 0);
      }
    }
    // ---- mask + scale
    const bool diag = (tile == qt);
#pragma unroll
    for (int kt = 0; kt < 4; ++kt) {
      int key = kt * 16 + l15;
#pragma unroll
      for (int j = 0; j < 4; ++j) {
        float s = sc[kt][j] * scale;
        if (diag && key > (w * 16 + l4 * 4 + j)) s = -1e30f;
        sc[kt][j] = s;
      }
    }
    // ---- online softmax (row = q, reduce across the 16-lane key group)
    f32x4 mt;
#pragma unroll
    for (int j = 0; j < 4; ++j)
      mt[j] = fmaxf(fmaxf(sc[0][j], sc[1][j]), fmaxf(sc[2][j], sc[3][j]));
#pragma unroll
    for (int msk = 1; msk < 16; msk <<= 1)
#pragma unroll
      for (int j = 0; j < 4; ++j) mt[j] = fmaxf(mt[j], __shfl_xor(mt[j], msk));
    f32x4 mnew, rs;
#pragma unroll
    for (int j = 0; j < 4; ++j) {
      mnew[j] = fmaxf(mrow[j], mt[j]);
      rs[j] = __expf(mrow[j] - mnew[j]);
    }
    f32x4 psum = {0.f, 0.f, 0.f, 0.f};
    unsigned short* pw = &Ps[w][0];
#pragma unroll
    for (int kt = 0; kt < 4; ++kt) {
      int kg = kt * 2 + (l15 >> 3), ke = l15 & 7;
#pragma unroll
      for (int j = 0; j < 4; ++j) {
        float p = __expf(sc[kt][j] - mnew[j]);
        psum[j] += p;
        int q = l4 * 4 + j;
        pw[q * 64 + ((kg ^ (q & 7)) * 8) + ke] = f2bf(p);
      }
    }
#pragma unroll
    for (int msk = 1; msk < 16; msk <<= 1)
#pragma unroll
      for (int j = 0; j < 4; ++j) psum[j] += __shfl_xor(psum[j], msk);
    mrow = mnew;
#pragma unroll
    for (int j = 0; j < 4; ++j) lrow[j] = lrow[j] * rs[j] + psum[j];
#pragma unroll
    for (int dt = 0; dt < 8; ++dt) O[dt] *= rs;
    // ---- O += P . V  (A = P rows q, B = V^T rows d; contraction over keys)
#pragma unroll
    for (int js = 0; js < 2; ++js) {
      int cpp = (js * 4 + l4) ^ (l15 & 7);
      s16x8 pf = *(const s16x8*)&Ps[w][l15 * 64 + cpp * 8];
#pragma unroll
      for (int dt = 0; dt < 8; ++dt) {
        int D = dt * 16 + l15;
        s16x8 vf = *(const s16x8*)&Vts[D * 64 + cpp * 8];   // D&7 == l15&7
        O[dt] = __builtin_amdgcn_mfma_f32_16x16x32_bf16(pf, vf, O[dt], 0, 0, 0);
      }
    }
    __syncthreads();                       // all waves done with Ks/Vts
    if (tile < qt) stageKV((tile + 1) * 64);
    __syncthreads();                       // staged tile visible
  }

  // ---- epilogue: normalize, sigmoid(z) gate, bf16 store
  f32x4 linv;
#pragma unroll
  for (int j = 0; j < 4; ++j) linv[j] = 1.f / lrow[j];
  const int tok0 = b * 1024 + qs0 + w * 16 + l4 * 4;
#pragma unroll
  for (int dt = 0; dt < 8; ++dt) {
    int d = dt * 16 + l15;
#pragma unroll
    for (int j = 0; j < 4; ++j) {
      size_t zidx = (size_t)(tok0 + j) * 5120 + h * 128 + d;
      size_t aidx = (size_t)(tok0 + j) * 2048 + h * 128 + d;
      float z = bf2f(Zb[zidx]);
      float o = O[dt][j] * linv[j];
      AO[aidx] = f2bf(o / (1.f + __expf(-z)));
    }
  }
}

// ---------------------------------------------------------------------------
// launcher
// ---------------------------------------------------------------------------
extern "C" void kernel_launch(void* const* d_in, const int* in_sizes, int n_in,
                              void* d_out, int out_size, void* d_ws, size_t ws_size,
                              hipStream_t stream) {
  const float* x       = (const float*)d_in[0];
  const float* in_ln   = (const float*)d_in[1];
  const float* Wq      = (const float*)d_in[2];
  const float* Wk      = (const float*)d_in[3];
  const float* Wv      = (const float*)d_in[4];
  const float* Wz      = (const float*)d_in[5];
  const float* Wo      = (const float*)d_in[6];
  const float* qn_w    = (const float*)d_in[7];
  const float* kn_w    = (const float*)d_in[8];
  const float* post_ln = (const float*)d_in[9];
  const float* Wg      = (const float*)d_in[10];
  const float* Wu      = (const float*)d_in[11];
  const float* Wd      = (const float*)d_in[12];

  const int T = 4096;   // B*S tokens

  char* ws = (char*)d_ws;
  size_t off = 0;
  auto alloc = [&](size_t bytes) -> void* {
    off = (off + 255) & ~(size_t)255;
    void* p = ws + off;
    off += bytes;
    return p;
  };

  // --- weights
  // fused QKVZ weight: rows 0-2047 Wq, 2048-2559 Wk, 2560-3071 Wv, 3072-5119 Wz
  unsigned short* Wqkvz_b = (unsigned short*)alloc((size_t)5120 * 2048 * 2);  // 20 MB
  unsigned short* Wo_b = (unsigned short*)alloc((size_t)2048 * 2048 * 2);     // 8 MB
  unsigned short* Wg_b = (unsigned short*)alloc((size_t)8192 * 2048 * 2);     // 32 MB
  unsigned short* Wu_b = (unsigned short*)alloc((size_t)8192 * 2048 * 2);     // 32 MB
  unsigned short* Wd_b = (unsigned short*)alloc((size_t)2048 * 8192 * 2);     // 32 MB

  // --- region R: 64 MB. Holds qkvz_bf (40 MB) + h_bf (16 MB) early; the whole
  // 64 MB is reused as gpre/gu (in-place silu-combine) once attention+Wo done.
  char* R = (char*)alloc((size_t)64 * 1024 * 1024);
  unsigned short* qkvz_bf = (unsigned short*)R;                       // 40 MB
  unsigned short* h_bf    = (unsigned short*)(R + (size_t)40 * 1024 * 1024); // 16 MB
  unsigned short* gu_bf   = (unsigned short*)R;                       // 64 MB (later)
  unsigned short* ao_bf   = h_bf;   // attention output (after h consumed)

  // --- x2 (f32, live to the end). Before Wo writes it, its space holds the
  // attention temps q_bf/k_bf/vt_bf (dead once attention completes).
  float* x2 = (float*)alloc((size_t)T * 2048 * 4);                    // 32 MB
  char* x2c = (char*)x2;
  unsigned short* vt_bf = (unsigned short*)(x2c);                     // 4 MB
  unsigned short* k_bf  = (unsigned short*)(x2c + 4194304);           // 4 MB
  unsigned short* q_bf  = (unsigned short*)(x2c + 8388608);           // 16 MB

  unsigned short* h2_bf = (unsigned short*)alloc((size_t)T * 2048 * 2); // 16 MB
  float* cosT = (float*)alloc((size_t)1024 * 64 * 4);
  float* sinT = (float*)alloc((size_t)1024 * 64 * 4);
  // total ~236.5 MB

  auto cvt = [&](const float* s, unsigned short* d, size_t n) {
    int n4 = (int)(n / 4);
    int blocks = (n4 + 255) / 256;
    if (blocks > 2048) blocks = 2048;
    k_f32_to_bf16<<<blocks, 256, 0, stream>>>(s, d, n4);
  };
  cvt(Wq, Wqkvz_b, (size_t)2048 * 2048);
  cvt(Wk, Wqkvz_b + (size_t)2048 * 2048, (size_t)512 * 2048);
  cvt(Wv, Wqkvz_b + (size_t)2560 * 2048, (size_t)512 * 2048);
  cvt(Wz, Wqkvz_b + (size_t)3072 * 2048, (size_t)2048 * 2048);
  cvt(Wo, Wo_b, (size_t)2048 * 2048);
  cvt(Wg, Wg_b, (size_t)8192 * 2048);
  cvt(Wu, Wu_b, (size_t)8192 * 2048);
  cvt(Wd, Wd_b, (size_t)2048 * 8192);

  k_rope_table<<<256, 256, 0, stream>>>(cosT, sinT);

  // h = rmsnorm(x, in_ln)
  k_rmsnorm<<<T, 256, 0, stream>>>(x, in_ln, h_bf);

  // fused QKVZ projection: [4096][5120] bf16
  k_gemm_bt<2><<<dim3(40, 32), 256, 0, stream>>>(h_bf, Wqkvz_b, nullptr, qkvz_bf, nullptr, T, 5120, 2048);

  // per-head q/k RMSNorm + RoPE -> bf16
  k_qknorm_rope<<<20480, 256, 0, stream>>>(qkvz_bf, q_bf, k_bf, qn_w, kn_w, cosT, sinT);

  // V -> V^T bf16 per (b,kv)
  k_transpose_v<<<dim3(16, 4, 4), 256, 0, stream>>>(qkvz_bf, vt_bf);

  // causal GQA attention (MFMA) + sigmoid(z) gate -> ao_bf
  k_attn_mfma<<<dim3(16, 16, 4), 256, 0, stream>>>(q_bf, k_bf, vt_bf, qkvz_bf + 3072, ao_bf);

  // x2 = x + ao @ Wo^T   (overwrites q/k/vt space — dead now)
  k_gemm_bt<1><<<dim3(16, 32), 256, 0, stream>>>(ao_bf, Wo_b, x2, nullptr, x, T, 2048, 2048);

  // h2 = rmsnorm(x2, post_ln)
  k_rmsnorm<<<T, 256, 0, stream>>>(x2, post_ln, h2_bf);

  // gu = h2 @ Wg^T  (bf16; overwrites qkvz/h region — dead now)
  k_gemm_bt<2><<<dim3(64, 32), 256, 0, stream>>>(h2_bf, Wg_b, nullptr, gu_bf, nullptr, T, 8192, 2048);

  // gu = silu(gu) * (h2 @ Wu^T)   (in place)
  k_gemm_bt<4><<<dim3(64, 32), 256, 0, stream>>>(h2_bf, Wu_b, nullptr, gu_bf, nullptr, T, 8192, 2048);

  // out = x2 + gu @ Wd^T
  k_gemm_bt<1><<<dim3(16, 32), 256, 0, stream>>>(gu_bf, Wd_b, (float*)d_out, nullptr, x2, T, 2048, 8192);
}

// Round 6
// 864.330 us; speedup vs baseline: 2.1410x; 1.0535x over previous
//
#include <hip/hip_runtime.h>

// ---------------------------------------------------------------------------
// DecoderLayer on MI355X. GEMM paths:
//  - k_gemm256: 256x256 tile, BK=64, 8 waves, 8-phase-style schedule with
//    counted vmcnt(12), LDS granule-XOR swizzle, setprio (QKVZ/Wg/Wu).
//  - k_gemm_bt: 128x128 2-phase dbuf (Wo/Wd, where 256² grids underfill).
// Attention: bf16 MFMA flash (unchanged).
// ---------------------------------------------------------------------------

typedef __attribute__((ext_vector_type(4))) float  f32x4;
typedef __attribute__((ext_vector_type(8))) short  s16x8;
typedef __attribute__((ext_vector_type(4))) unsigned short u16x4;

#define DEVI static __device__ __forceinline__

DEVI unsigned short f2bf(float f) {
  union { float f; unsigned u; } a; a.f = f;
  unsigned r = a.u + 0x7FFFu + ((a.u >> 16) & 1u);
  return (unsigned short)(r >> 16);
}
DEVI float bf2f(unsigned short u) {
  union { unsigned u; float f; } a; a.u = (unsigned)u << 16; return a.f;
}

DEVI void gload16(const void* g, void* l) {
  __builtin_amdgcn_global_load_lds(
      (const __attribute__((address_space(1))) unsigned int*)(unsigned long long)g,
      (__attribute__((address_space(3))) unsigned int*)(unsigned int)(unsigned long long)l,
      16, 0, 0);
}

#define MFMA_BF16 __builtin_amdgcn_mfma_f32_16x16x32_bf16
#define WAITV12() asm volatile("s_waitcnt vmcnt(12)" ::: "memory")
#define WAITV0()  asm volatile("s_waitcnt vmcnt(0)" ::: "memory")
#define LGKM0()   do { asm volatile("s_waitcnt lgkmcnt(0)" ::: "memory"); \
                       __builtin_amdgcn_sched_barrier(0); } while (0)

// ---------------------------------------------------------------------------
__global__ void k_f32_to_bf16(const float* __restrict__ src,
                              unsigned short* __restrict__ dst, int n4) {
  int i = blockIdx.x * blockDim.x + threadIdx.x;
  int stride = gridDim.x * blockDim.x;
  for (; i < n4; i += stride) {
    f32x4 v = ((const f32x4*)src)[i];
    u16x4 o;
    o.x = f2bf(v.x); o.y = f2bf(v.y); o.z = f2bf(v.z); o.w = f2bf(v.w);
    ((u16x4*)dst)[i] = o;
  }
}

// ---------------------------------------------------------------------------
__global__ __launch_bounds__(256) void k_rmsnorm(const float* __restrict__ x,
                                                 const float* __restrict__ w,
                                                 unsigned short* __restrict__ out) {
  const int row = blockIdx.x, t = threadIdx.x;
  const f32x4* xr = (const f32x4*)(x + (size_t)row * 2048);
  f32x4 a = xr[t * 2], b = xr[t * 2 + 1];
  float ss = a.x*a.x + a.y*a.y + a.z*a.z + a.w*a.w
           + b.x*b.x + b.y*b.y + b.z*b.z + b.w*b.w;
#pragma unroll
  for (int m = 32; m; m >>= 1) ss += __shfl_xor(ss, m);
  __shared__ float sred[4];
  if ((t & 63) == 0) sred[t >> 6] = ss;
  __syncthreads();
  float tot = sred[0] + sred[1] + sred[2] + sred[3];
  float r = rsqrtf(tot * (1.0f / 2048.0f) + 1e-6f);
  const f32x4* wr = (const f32x4*)w;
  f32x4 w1 = wr[t * 2], w2 = wr[t * 2 + 1];
  u16x4 o1, o2;
  o1.x = f2bf(a.x * r * (1.f + w1.x)); o1.y = f2bf(a.y * r * (1.f + w1.y));
  o1.z = f2bf(a.z * r * (1.f + w1.z)); o1.w = f2bf(a.w * r * (1.f + w1.w));
  o2.x = f2bf(b.x * r * (1.f + w2.x)); o2.y = f2bf(b.y * r * (1.f + w2.y));
  o2.z = f2bf(b.z * r * (1.f + w2.z)); o2.w = f2bf(b.w * r * (1.f + w2.w));
  u16x4* od = (u16x4*)(out + (size_t)row * 2048);
  od[t * 2] = o1; od[t * 2 + 1] = o2;
}

// ---------------------------------------------------------------------------
__global__ void k_rope_table(float* __restrict__ cosT, float* __restrict__ sinT) {
  int i = blockIdx.x * blockDim.x + threadIdx.x;
  int tpos = i >> 6, f = i & 63;
  double inv = exp(-0.14391156831212787 * (double)f);
  float ang = (float)tpos * (float)inv;
  cosT[i] = cosf(ang);
  sinT[i] = sinf(ang);
}

// ---------------------------------------------------------------------------
__global__ __launch_bounds__(256) void k_qknorm_rope(
    const unsigned short* __restrict__ QKVZ,
    unsigned short* __restrict__ Qo, unsigned short* __restrict__ Ko,
    const float* __restrict__ qw, const float* __restrict__ kw,
    const float* __restrict__ cosT, const float* __restrict__ sinT) {
  int gid = blockIdx.x * 4 + (threadIdx.x >> 6);
  int lane = threadIdx.x & 63;
  int tok = gid / 20, hh = gid % 20;
  const unsigned short* p; const float* w; unsigned short* o;
  if (hh < 16) { p = QKVZ + (size_t)tok * 5120 + hh * 128; w = qw;
                 o = Qo + (size_t)tok * 2048 + hh * 128; }
  else         { p = QKVZ + (size_t)tok * 5120 + 2048 + (hh - 16) * 128; w = kw;
                 o = Ko + (size_t)tok * 512 + (hh - 16) * 128; }
  float x1 = bf2f(p[lane]), x2 = bf2f(p[lane + 64]);
  float ss = x1 * x1 + x2 * x2;
#pragma unroll
  for (int m = 1; m < 64; m <<= 1) ss += __shfl_xor(ss, m);
  float r = rsqrtf(ss * (1.0f / 128.0f) + 1e-6f);
  float n1 = x1 * r * (1.f + w[lane]);
  float n2 = x2 * r * (1.f + w[lane + 64]);
  int s = tok & 1023;
  float c = cosT[s * 64 + lane], sn = sinT[s * 64 + lane];
  o[lane]      = f2bf(n1 * c - n2 * sn);
  o[lane + 64] = f2bf(n2 * c + n1 * sn);
}

// ---------------------------------------------------------------------------
__global__ __launch_bounds__(256) void k_transpose_v(const unsigned short* __restrict__ QKVZ,
                                                     unsigned short* __restrict__ Vt) {
  __shared__ unsigned short Vl[128 * 66];
  const int t = threadIdx.x;
  const int key0 = blockIdx.x * 64, kvh = blockIdx.y, b = blockIdx.z;
#pragma unroll
  for (int i = 0; i < 4; ++i) {
    int g = i * 256 + t;
    int key = g >> 4, dc = (g & 15) * 8;
    s16x8 v = *(const s16x8*)&QKVZ[(size_t)(b * 1024 + key0 + key) * 5120 + 2560 + kvh * 128 + dc];
#pragma unroll
    for (int j = 0; j < 8; ++j) Vl[(dc + j) * 66 + key] = (unsigned short)v[j];
  }
  __syncthreads();
#pragma unroll
  for (int i = 0; i < 8; ++i) {
    int g = i * 256 + t;
    int d = g >> 4, kc = g & 15;
    u16x4 o;
#pragma unroll
    for (int j = 0; j < 4; ++j) o[j] = Vl[d * 66 + kc * 4 + j];
    *(u16x4*)&Vt[((size_t)(b * 4 + kvh) * 128 + d) * 1024 + key0 + kc * 4] = o;
  }
}

// ---------------------------------------------------------------------------
// 256x256 GEMM, BK=64, 8 waves (2M x 4N), per-wave 128x64 out (8x4 frags).
// 4 phases per K-tile (C-quadrants), counted vmcnt(12), dead-row staging
// 2 K-tiles ahead, granule-XOR LDS swizzle, setprio around MFMA clusters.
// EPI 2: store bf16.  EPI 4: in-place bf16( silu(Cb[idx]) * acc ).
// ---------------------------------------------------------------------------
template <int EPI>
__global__ __launch_bounds__(512) void k_gemm256(
    const unsigned short* __restrict__ A, const unsigned short* __restrict__ B,
    unsigned short* __restrict__ Cb, int M, int N, int K) {
  __shared__ unsigned short As[2][256][64];
  __shared__ unsigned short Bs[2][256][64];

  const int t = threadIdx.x, lane = t & 63, w = t >> 6;
  const int wr = w >> 2, wc = w & 3;          // 2M x 4N wave grid
  const int l15 = lane & 15, l4 = lane >> 4;
  const int xg = l15 & 7;
  const int hb = wc >> 1, cl = wc & 1;

  // XCD-chunk + GM=8 supertile raster (nwg % 8 == 0)
  const int nbx = gridDim.x;
  const int nwg = nbx * gridDim.y;
  const int bid = blockIdx.y * nbx + blockIdx.x;
  const int sw = (bid & 7) * (nwg >> 3) + (bid >> 3);
  const int tpg = 8 * nbx;
  const int mi_ = (sw / tpg) * 8 + (sw & 7);
  const int ni_ = (sw % tpg) >> 3;
  const int m0 = mi_ * 256, n0 = ni_ * 256;

  const int NT = K >> 6;

  // staging: source granule pre-swizzled so read-side XOR recovers linear k
  auto stageA = [&](int tt, int pm) {           // pm strip: rows wr*128+pm*64..+64
    int dd = tt & 1;
#pragma unroll
    for (int c = 0; c < 2; ++c) {
      int r0 = wr * 128 + pm * 64 + wc * 16 + c * 8;
      int r = r0 + (lane >> 3);
      int gs = (lane & 7) ^ (r & 7);
      gload16(A + (size_t)(m0 + r) * K + tt * 64 + gs * 8, (void*)&As[dd][r0][0]);
    }
  };
  auto stageB = [&](int tt, int pn) {           // pn strip: (row&63) in [pn*32, +32)
    int dd = tt & 1;
#pragma unroll
    for (int c = 0; c < 2; ++c) {
      int r0 = hb * 128 + cl * 64 + pn * 32 + wr * 16 + c * 8;
      int r = r0 + (lane >> 3);
      int gs = (lane & 7) ^ (r & 7);
      gload16(B + (size_t)(n0 + r) * K + tt * 64 + gs * 8, (void*)&Bs[dd][r0][0]);
    }
  };

  // prologue: tiles 0 and 1, order [A-low, B-pn0, B-pn1, A-high]
  stageA(0, 0); stageB(0, 0); stageB(0, 1); stageA(0, 1);
  stageA(1, 0); stageB(1, 0); stageB(1, 1); stageA(1, 1);

  f32x4 acc[8][4] = {};
  s16x8 afL[4][2], afH[4][2], bf0[2][2], bf1[2][2];

  for (int u = 0; u < NT; ++u) {
    const int cur = u & 1;
    const bool deep = (u + 2 < NT);

    // ---------- phase 0: quadrant (mi 0-3, ni 0-1) — reads A-low, B-pn0 ----
    if (deep) WAITV12(); else WAITV0();
    __builtin_amdgcn_s_barrier();
#pragma unroll
    for (int i = 0; i < 4; ++i) {
      int row = wr * 128 + i * 16 + l15;
      afL[i][0] = *(const s16x8*)&As[cur][row][(l4 ^ xg) * 8];
      afL[i][1] = *(const s16x8*)&As[cur][row][((l4 ^ xg) ^ 4) * 8];
    }
#pragma unroll
    for (int n = 0; n < 2; ++n) {
      int row = wc * 64 + n * 16 + l15;
      bf0[n][0] = *(const s16x8*)&Bs[cur][row][(l4 ^ xg) * 8];
      bf0[n][1] = *(const s16x8*)&Bs[cur][row][((l4 ^ xg) ^ 4) * 8];
    }
    LGKM0();
    __builtin_amdgcn_s_setprio(1);
#pragma unroll
    for (int i = 0; i < 4; ++i)
#pragma unroll
      for (int n = 0; n < 2; ++n) {
        acc[i][n] = MFMA_BF16(afL[i][0], bf0[n][0], acc[i][n], 0, 0, 0);
        acc[i][n] = MFMA_BF16(afL[i][1], bf0[n][1], acc[i][n], 0, 0, 0);
      }
    __builtin_amdgcn_s_setprio(0);
    __builtin_amdgcn_s_barrier();

    // ---------- phase 1: (mi 0-3, ni 2-3) — reads B-pn1; stages A-low(u+2) --
    if (deep) stageA(u + 2, 0);
    if (deep) WAITV12(); else WAITV0();
    __builtin_amdgcn_s_barrier();
#pragma unroll
    for (int n = 0; n < 2; ++n) {
      int row = wc * 64 + (2 + n) * 16 + l15;
      bf1[n][0] = *(const s16x8*)&Bs[cur][row][(l4 ^ xg) * 8];
      bf1[n][1] = *(const s16x8*)&Bs[cur][row][((l4 ^ xg) ^ 4) * 8];
    }
    LGKM0();
    __builtin_amdgcn_s_setprio(1);
#pragma unroll
    for (int i = 0; i < 4; ++i)
#pragma unroll
      for (int n = 0; n < 2; ++n) {
        acc[i][2 + n] = MFMA_BF16(afL[i][0], bf1[n][0], acc[i][2 + n], 0, 0, 0);
        acc[i][2 + n] = MFMA_BF16(afL[i][1], bf1[n][1], acc[i][2 + n], 0, 0, 0);
      }
    __builtin_amdgcn_s_setprio(0);
    __builtin_amdgcn_s_barrier();

    // ---------- phase 2: (mi 4-7, ni 2-3) — reads A-high; stages B(u+2) -----
    if (deep) { stageB(u + 2, 0); stageB(u + 2, 1); }
    if (deep) WAITV12(); else WAITV0();
    __builtin_amdgcn_s_barrier();
#pragma unroll
    for (int i = 0; i < 4; ++i) {
      int row = wr * 128 + 64 + i * 16 + l15;
      afH[i][0] = *(const s16x8*)&As[cur][row][(l4 ^ xg) * 8];
      afH[i][1] = *(const s16x8*)&As[cur][row][((l4 ^ xg) ^ 4) * 8];
    }
    LGKM0();
    __builtin_amdgcn_s_setprio(1);
#pragma unroll
    for (int i = 0; i < 4; ++i)
#pragma unroll
      for (int n = 0; n < 2; ++n) {
        acc[4 + i][2 + n] = MFMA_BF16(afH[i][0], bf1[n][0], acc[4 + i][2 + n], 0, 0, 0);
        acc[4 + i][2 + n] = MFMA_BF16(afH[i][1], bf1[n][1], acc[4 + i][2 + n], 0, 0, 0);
      }
    __builtin_amdgcn_s_setprio(0);
    __builtin_amdgcn_s_barrier();

    // ---------- phase 3: (mi 4-7, ni 0-1) — no reads; stages A-high(u+2) ----
    if (deep) stageA(u + 2, 1);
    __builtin_amdgcn_s_barrier();
    __builtin_amdgcn_s_setprio(1);
#pragma unroll
    for (int i = 0; i < 4; ++i)
#pragma unroll
      for (int n = 0; n < 2; ++n) {
        acc[4 + i][n] = MFMA_BF16(afH[i][0], bf0[n][0], acc[4 + i][n], 0, 0, 0);
        acc[4 + i][n] = MFMA_BF16(afH[i][1], bf0[n][1], acc[4 + i][n], 0, 0, 0);
      }
    __builtin_amdgcn_s_setprio(0);
    __builtin_amdgcn_s_barrier();
  }

  // ---- epilogue: C layout col = l15, row = l4*4 + j
#pragma unroll
  for (int mi = 0; mi < 8; ++mi)
#pragma unroll
    for (int ni = 0; ni < 4; ++ni) {
      int col = n0 + wc * 64 + ni * 16 + l15;
#pragma unroll
      for (int j = 0; j < 4; ++j) {
        int row = m0 + wr * 128 + mi * 16 + l4 * 4 + j;
        size_t idx = (size_t)row * N + col;
        float g = acc[mi][ni][j];
        if constexpr (EPI == 2) {
          Cb[idx] = f2bf(g);
        } else {
          float gv = bf2f(Cb[idx]);
          float sg = gv / (1.f + __expf(-gv));
          Cb[idx] = f2bf(sg * g);
        }
      }
    }
}

// ---------------------------------------------------------------------------
// 128x128 2-phase GEMM (Wo / Wd). EPI 1: f32 + residual.
// ---------------------------------------------------------------------------
template <int EPI>
__global__ __launch_bounds__(256) void k_gemm_bt(
    const unsigned short* __restrict__ A, const unsigned short* __restrict__ B,
    float* __restrict__ Cf, unsigned short* __restrict__ Cb,
    const float* __restrict__ res,
    int M, int N, int K) {
  __shared__ unsigned short As[2][128 * 32];
  __shared__ unsigned short Bs[2][128 * 32];

  const int t = threadIdx.x, lane = t & 63, w = t >> 6;
  const int wr = w >> 1, wc = w & 1;
  const int nbx = gridDim.x;
  const int nwg = nbx * gridDim.y;
  const int bid = blockIdx.y * nbx + blockIdx.x;
  const int sw = (bid & 7) * (nwg >> 3) + (bid >> 3);
  const int tpg = 8 * nbx;
  const int mi = (sw / tpg) * 8 + (sw & 7);
  const int ni = (sw % tpg) >> 3;
  const int m0 = mi * 128, n0 = ni * 128;

  f32x4 acc[4][4] = {};

  const int srow = lane >> 2;
  const int scol = (lane & 3) * 8;

  auto stage = [&](int kk, int sel) {
#pragma unroll
    for (int r = 0; r < 2; ++r) {
      int row = 16 * w + srow + 64 * r;
      gload16(A + (size_t)(m0 + row) * K + kk + scol, (void*)&As[sel][w * 512 + r * 2048]);
      gload16(B + (size_t)(n0 + row) * K + kk + scol, (void*)&Bs[sel][w * 512 + r * 2048]);
    }
  };

  stage(0, 0);
  __syncthreads();

  const int nk = K >> 5;
  for (int tk = 0; tk < nk; ++tk) {
    const int cur = tk & 1;
    if (tk + 1 < nk) stage((tk + 1) << 5, cur ^ 1);

    s16x8 af[4], bf_[4];
#pragma unroll
    for (int i = 0; i < 4; ++i) {
      af[i]  = *(const s16x8*)&As[cur][(wr * 64 + i * 16 + (lane & 15)) * 32 + (lane >> 4) * 8];
      bf_[i] = *(const s16x8*)&Bs[cur][(wc * 64 + i * 16 + (lane & 15)) * 32 + (lane >> 4) * 8];
    }
#pragma unroll
    for (int mi2 = 0; mi2 < 4; ++mi2)
#pragma unroll
      for (int ni2 = 0; ni2 < 4; ++ni2)
        acc[mi2][ni2] = MFMA_BF16(af[mi2], bf_[ni2], acc[mi2][ni2], 0, 0, 0);
    __syncthreads();
  }

  const int er = (lane >> 4) * 4;
  const int ec = lane & 15;
#pragma unroll
  for (int mi2 = 0; mi2 < 4; ++mi2)
#pragma unroll
    for (int ni2 = 0; ni2 < 4; ++ni2) {
      int col = n0 + wc * 64 + ni2 * 16 + ec;
#pragma unroll
      for (int j = 0; j < 4; ++j) {
        int row = m0 + wr * 64 + mi2 * 16 + er + j;
        size_t idx = (size_t)row * N + col;
        float g = acc[mi2][ni2][j];
        if constexpr (EPI == 0) {
          Cf[idx] = g;
        } else if constexpr (EPI == 1) {
          Cf[idx] = g + res[idx];
        } else if constexpr (EPI == 2) {
          Cb[idx] = f2bf(g);
        } else {
          float gv = bf2f(Cb[idx]);
          float sg = gv / (1.f + __expf(-gv));
          Cb[idx] = f2bf(sg * g);
        }
      }
    }
}

// ---------------------------------------------------------------------------
// Causal GQA attention, bf16 MFMA flash (unchanged from round 4/5).
// ---------------------------------------------------------------------------
__global__ __launch_bounds__(256) void k_attn_mfma(
    const unsigned short* __restrict__ Qb,
    const unsigned short* __restrict__ Kb,
    const unsigned short* __restrict__ Vt,
    const unsigned short* __restrict__ Zb,
    unsigned short* __restrict__ AO) {
  __shared__ unsigned short Qs[64 * 128];
  __shared__ unsigned short Ks[64 * 128];
  __shared__ unsigned short Vts[128 * 64];
  __shared__ unsigned short Ps[4][16 * 64];

  const int t = threadIdx.x, lane = t & 63, w = t >> 6;
  const int l15 = lane & 15, l4 = lane >> 4;
  const int qt = (int)gridDim.x - 1 - (int)blockIdx.x;
  const int qs0 = qt * 64;
  const int h = blockIdx.y, b = blockIdx.z;
  const int kv = h >> 2;

  {
    const unsigned short* qb = Qb + (size_t)(b * 1024 + qs0) * 2048 + h * 128;
#pragma unroll
    for (int r = 0; r < 4; ++r) {
      int row = r * 16 + w * 4 + (lane >> 4);
      int cp = lane & 15;
      int c = (cp & 8) | ((cp & 7) ^ (row & 7));
      gload16(qb + (size_t)row * 2048 + c * 8, (void*)&Qs[(r * 256 + w * 64) * 8]);
    }
  }

  auto stageKV = [&](int j0) {
    const unsigned short* kb = Kb + (size_t)(b * 1024 + j0) * 512 + kv * 128;
#pragma unroll
    for (int r = 0; r < 4; ++r) {
      int row = r * 16 + w * 4 + (lane >> 4);
      int cp = lane & 15;
      int c = (cp & 8) | ((cp & 7) ^ (row & 7));
      gload16(kb + (size_t)row * 512 + c * 8, (void*)&Ks[(r * 256 + w * 64) * 8]);
    }
    const unsigned short* vb = Vt + (size_t)(b * 4 + kv) * 131072 + j0;
#pragma unroll
    for (int r = 0; r < 4; ++r) {
      int row = r * 32 + w * 8 + (lane >> 3);
      int cp = lane & 7;
      int c = cp ^ (row & 7);
      gload16(vb + (size_t)row * 1024 + c * 8, (void*)&Vts[(r * 256 + w * 64) * 8]);
    }
  };

  stageKV(0);
  __syncthreads();

  s16x8 qf[4];
#pragma unroll
  for (int ks = 0; ks < 4; ++ks) {
    int R = w * 16 + l15;
    int c = ks * 4 + l4;
    int cp = (c & 8) | ((c & 7) ^ (R & 7));
    qf[ks] = *(const s16x8*)&Qs[R * 128 + cp * 8];
  }

  f32x4 O[8] = {};
  f32x4 mrow = {-1e30f, -1e30f, -1e30f, -1e30f};
  f32x4 lrow = {0.f, 0.f, 0.f, 0.f};
  const float scale = 0.088388347648318447f;

  for (int tile = 0; tile <= qt; ++tile) {
    f32x4 sc[4] = {};
#pragma unroll
    for (int ks = 0; ks < 4; ++ks) {
#pragma unroll
      for (int kt = 0; kt < 4; ++kt) {
        int R = kt * 16 + l15;
        int c = ks * 4 + l4;
        int cp = (c & 8) | ((c & 7) ^ (R & 7));
        s16x8 kf = *(const s16x8*)&Ks[R * 128 + cp * 8];
        sc[kt] = MFMA_BF16(qf[ks], kf, sc[kt], 0, 0, 0);
      }
    }
    const bool diag = (tile == qt);
#pragma unroll
    for (int kt = 0; kt < 4; ++kt) {
      int key = kt * 16 + l15;
#pragma unroll
      for (int j = 0; j < 4; ++j) {
        float s = sc[kt][j] * scale;
        if (diag && key > (w * 16 + l4 * 4 + j)) s = -1e30f;
        sc[kt][j] = s;
      }
    }
    f32x4 mt;
#pragma unroll
    for (int j = 0; j < 4; ++j)
      mt[j] = fmaxf(fmaxf(sc[0][j], sc[1][j]), fmaxf(sc[2][j], sc[3][j]));
#pragma unroll
    for (int msk = 1; msk < 16; msk <<= 1)
#pragma unroll
      for (int j = 0; j < 4; ++j) mt[j] = fmaxf(mt[j], __shfl_xor(mt[j], msk));
    f32x4 mnew, rs;
#pragma unroll
    for (int j = 0; j < 4; ++j) {
      mnew[j] = fmaxf(mrow[j], mt[j]);
      rs[j] = __expf(mrow[j] - mnew[j]);
    }
    f32x4 psum = {0.f, 0.f, 0.f, 0.f};
    unsigned short* pw = &Ps[w][0];
#pragma unroll
    for (int kt = 0; kt < 4; ++kt) {
      int kg = kt * 2 + (l15 >> 3), ke = l15 & 7;
#pragma unroll
      for (int j = 0; j < 4; ++j) {
        float p = __expf(sc[kt][j] - mnew[j]);
        psum[j] += p;
        int q = l4 * 4 + j;
        pw[q * 64 + ((kg ^ (q & 7)) * 8) + ke] = f2bf(p);
      }
    }
#pragma unroll
    for (int msk = 1; msk < 16; msk <<= 1)
#pragma unroll
      for (int j = 0; j < 4; ++j) psum[j] += __shfl_xor(psum[j], msk);
    mrow = mnew;
#pragma unroll
    for (int j = 0; j < 4; ++j) lrow[j] = lrow[j] * rs[j] + psum[j];
#pragma unroll
    for (int dt = 0; dt < 8; ++dt) O[dt] *= rs;
#pragma unroll
    for (int js = 0; js < 2; ++js) {
      int cpp = (js * 4 + l4) ^ (l15 & 7);
      s16x8 pf = *(const s16x8*)&Ps[w][l15 * 64 + cpp * 8];
#pragma unroll
      for (int dt = 0; dt < 8; ++dt) {
        int D = dt * 16 + l15;
        s16x8 vf = *(const s16x8*)&Vts[D * 64 + cpp * 8];
        O[dt] = MFMA_BF16(pf, vf, O[dt], 0, 0, 0);
      }
    }
    __syncthreads();
    if (tile < qt) stageKV((tile + 1) * 64);
    __syncthreads();
  }

  f32x4 linv;
#pragma unroll
  for (int j = 0; j < 4; ++j) linv[j] = 1.f / lrow[j];
  const int tok0 = b * 1024 + qs0 + w * 16 + l4 * 4;
#pragma unroll
  for (int dt = 0; dt < 8; ++dt) {
    int d = dt * 16 + l15;
#pragma unroll
    for (int j = 0; j < 4; ++j) {
      size_t zidx = (size_t)(tok0 + j) * 5120 + h * 128 + d;
      size_t aidx = (size_t)(tok0 + j) * 2048 + h * 128 + d;
      float z = bf2f(Zb[zidx]);
      float o = O[dt][j] * linv[j];
      AO[aidx] = f2bf(o / (1.f + __expf(-z)));
    }
  }
}

// ---------------------------------------------------------------------------
// launcher
// ---------------------------------------------------------------------------
extern "C" void kernel_launch(void* const* d_in, const int* in_sizes, int n_in,
                              void* d_out, int out_size, void* d_ws, size_t ws_size,
                              hipStream_t stream) {
  const float* x       = (const float*)d_in[0];
  const float* in_ln   = (const float*)d_in[1];
  const float* Wq      = (const float*)d_in[2];
  const float* Wk      = (const float*)d_in[3];
  const float* Wv      = (const float*)d_in[4];
  const float* Wz      = (const float*)d_in[5];
  const float* Wo      = (const float*)d_in[6];
  const float* qn_w    = (const float*)d_in[7];
  const float* kn_w    = (const float*)d_in[8];
  const float* post_ln = (const float*)d_in[9];
  const float* Wg      = (const float*)d_in[10];
  const float* Wu      = (const float*)d_in[11];
  const float* Wd      = (const float*)d_in[12];

  const int T = 4096;

  char* ws = (char*)d_ws;
  size_t off = 0;
  auto alloc = [&](size_t bytes) -> void* {
    off = (off + 255) & ~(size_t)255;
    void* p = ws + off;
    off += bytes;
    return p;
  };

  unsigned short* Wqkvz_b = (unsigned short*)alloc((size_t)5120 * 2048 * 2);
  unsigned short* Wo_b = (unsigned short*)alloc((size_t)2048 * 2048 * 2);
  unsigned short* Wg_b = (unsigned short*)alloc((size_t)8192 * 2048 * 2);
  unsigned short* Wu_b = (unsigned short*)alloc((size_t)8192 * 2048 * 2);
  unsigned short* Wd_b = (unsigned short*)alloc((size_t)2048 * 8192 * 2);

  char* R = (char*)alloc((size_t)64 * 1024 * 1024);
  unsigned short* qkvz_bf = (unsigned short*)R;
  unsigned short* h_bf    = (unsigned short*)(R + (size_t)40 * 1024 * 1024);
  unsigned short* gu_bf   = (unsigned short*)R;
  unsigned short* ao_bf   = h_bf;

  float* x2 = (float*)alloc((size_t)T * 2048 * 4);
  char* x2c = (char*)x2;
  unsigned short* vt_bf = (unsigned short*)(x2c);
  unsigned short* k_bf  = (unsigned short*)(x2c + 4194304);
  unsigned short* q_bf  = (unsigned short*)(x2c + 8388608);

  unsigned short* h2_bf = (unsigned short*)alloc((size_t)T * 2048 * 2);
  float* cosT = (float*)alloc((size_t)1024 * 64 * 4);
  float* sinT = (float*)alloc((size_t)1024 * 64 * 4);

  auto cvt = [&](const float* s, unsigned short* d, size_t n) {
    int n4 = (int)(n / 4);
    int blocks = (n4 + 255) / 256;
    if (blocks > 2048) blocks = 2048;
    k_f32_to_bf16<<<blocks, 256, 0, stream>>>(s, d, n4);
  };
  cvt(Wq, Wqkvz_b, (size_t)2048 * 2048);
  cvt(Wk, Wqkvz_b + (size_t)2048 * 2048, (size_t)512 * 2048);
  cvt(Wv, Wqkvz_b + (size_t)2560 * 2048, (size_t)512 * 2048);
  cvt(Wz, Wqkvz_b + (size_t)3072 * 2048, (size_t)2048 * 2048);
  cvt(Wo, Wo_b, (size_t)2048 * 2048);
  cvt(Wg, Wg_b, (size_t)8192 * 2048);
  cvt(Wu, Wu_b, (size_t)8192 * 2048);
  cvt(Wd, Wd_b, (size_t)2048 * 8192);

  k_rope_table<<<256, 256, 0, stream>>>(cosT, sinT);

  // h = rmsnorm(x, in_ln)
  k_rmsnorm<<<T, 256, 0, stream>>>(x, in_ln, h_bf);

  // fused QKVZ projection: [4096][5120] bf16 (256² 8-phase)
  k_gemm256<2><<<dim3(20, 16), 512, 0, stream>>>(h_bf, Wqkvz_b, qkvz_bf, T, 5120, 2048);

  // per-head q/k RMSNorm + RoPE -> bf16
  k_qknorm_rope<<<20480, 256, 0, stream>>>(qkvz_bf, q_bf, k_bf, qn_w, kn_w, cosT, sinT);

  // V -> V^T bf16 per (b,kv)
  k_transpose_v<<<dim3(16, 4, 4), 256, 0, stream>>>(qkvz_bf, vt_bf);

  // causal GQA attention (MFMA) + sigmoid(z) gate -> ao_bf
  k_attn_mfma<<<dim3(16, 16, 4), 256, 0, stream>>>(q_bf, k_bf, vt_bf, qkvz_bf + 3072, ao_bf);

  // x2 = x + ao @ Wo^T  (128² kernel: 256²-grid would underfill at N=2048)
  k_gemm_bt<1><<<dim3(16, 32), 256, 0, stream>>>(ao_bf, Wo_b, x2, nullptr, x, T, 2048, 2048);

  // h2 = rmsnorm(x2, post_ln)
  k_rmsnorm<<<T, 256, 0, stream>>>(x2, post_ln, h2_bf);

  // gu = h2 @ Wg^T  (bf16, 256² 8-phase)
  k_gemm256<2><<<dim3(32, 16), 512, 0, stream>>>(h2_bf, Wg_b, gu_bf, T, 8192, 2048);

  // gu = silu(gu) * (h2 @ Wu^T)  (in place, 256² 8-phase)
  k_gemm256<4><<<dim3(32, 16), 512, 0, stream>>>(h2_bf, Wu_b, gu_bf, T, 8192, 2048);

  // out = x2 + gu @ Wd^T  (128² kernel)
  k_gemm_bt<1><<<dim3(16, 32), 256, 0, stream>>>(gu_bf, Wd_b, (float*)d_out, nullptr, x2, T, 2048, 8192);
}

// Round 7
// 853.261 us; speedup vs baseline: 2.1688x; 1.0130x over previous
//
#include <hip/hip_runtime.h>

// ---------------------------------------------------------------------------
// DecoderLayer on MI355X. GEMM paths:
//  - k_gemm256: 256x256 tile, BK=64, 8 waves, m201-style 4-phase/K-tile
//    schedule: reads-before-barrier, ONE counted vmcnt(8) per K-tile,
//    dead-region staging 2 K-tiles ahead, granule-XOR swizzle, setprio.
//  - k_gemm_bt: 128x128 2-phase dbuf (Wo/Wd, where 256² grids underfill).
// Attention: bf16 MFMA flash (unchanged).
// ---------------------------------------------------------------------------

typedef __attribute__((ext_vector_type(4))) float  f32x4;
typedef __attribute__((ext_vector_type(8))) short  s16x8;
typedef __attribute__((ext_vector_type(4))) unsigned short u16x4;

#define DEVI static __device__ __forceinline__

DEVI unsigned short f2bf(float f) {
  union { float f; unsigned u; } a; a.f = f;
  unsigned r = a.u + 0x7FFFu + ((a.u >> 16) & 1u);
  return (unsigned short)(r >> 16);
}
DEVI float bf2f(unsigned short u) {
  union { unsigned u; float f; } a; a.u = (unsigned)u << 16; return a.f;
}

DEVI void gload16(const void* g, void* l) {
  __builtin_amdgcn_global_load_lds(
      (const __attribute__((address_space(1))) unsigned int*)(unsigned long long)g,
      (__attribute__((address_space(3))) unsigned int*)(unsigned int)(unsigned long long)l,
      16, 0, 0);
}

#define MFMA_BF16 __builtin_amdgcn_mfma_f32_16x16x32_bf16
#define WAITV8()  asm volatile("s_waitcnt vmcnt(8)" ::: "memory")
#define WAITV0()  asm volatile("s_waitcnt vmcnt(0)" ::: "memory")

// ---------------------------------------------------------------------------
__global__ void k_f32_to_bf16(const float* __restrict__ src,
                              unsigned short* __restrict__ dst, int n4) {
  int i = blockIdx.x * blockDim.x + threadIdx.x;
  int stride = gridDim.x * blockDim.x;
  for (; i < n4; i += stride) {
    f32x4 v = ((const f32x4*)src)[i];
    u16x4 o;
    o.x = f2bf(v.x); o.y = f2bf(v.y); o.z = f2bf(v.z); o.w = f2bf(v.w);
    ((u16x4*)dst)[i] = o;
  }
}

// ---------------------------------------------------------------------------
__global__ __launch_bounds__(256) void k_rmsnorm(const float* __restrict__ x,
                                                 const float* __restrict__ w,
                                                 unsigned short* __restrict__ out) {
  const int row = blockIdx.x, t = threadIdx.x;
  const f32x4* xr = (const f32x4*)(x + (size_t)row * 2048);
  f32x4 a = xr[t * 2], b = xr[t * 2 + 1];
  float ss = a.x*a.x + a.y*a.y + a.z*a.z + a.w*a.w
           + b.x*b.x + b.y*b.y + b.z*b.z + b.w*b.w;
#pragma unroll
  for (int m = 32; m; m >>= 1) ss += __shfl_xor(ss, m);
  __shared__ float sred[4];
  if ((t & 63) == 0) sred[t >> 6] = ss;
  __syncthreads();
  float tot = sred[0] + sred[1] + sred[2] + sred[3];
  float r = rsqrtf(tot * (1.0f / 2048.0f) + 1e-6f);
  const f32x4* wr = (const f32x4*)w;
  f32x4 w1 = wr[t * 2], w2 = wr[t * 2 + 1];
  u16x4 o1, o2;
  o1.x = f2bf(a.x * r * (1.f + w1.x)); o1.y = f2bf(a.y * r * (1.f + w1.y));
  o1.z = f2bf(a.z * r * (1.f + w1.z)); o1.w = f2bf(a.w * r * (1.f + w1.w));
  o2.x = f2bf(b.x * r * (1.f + w2.x)); o2.y = f2bf(b.y * r * (1.f + w2.y));
  o2.z = f2bf(b.z * r * (1.f + w2.z)); o2.w = f2bf(b.w * r * (1.f + w2.w));
  u16x4* od = (u16x4*)(out + (size_t)row * 2048);
  od[t * 2] = o1; od[t * 2 + 1] = o2;
}

// ---------------------------------------------------------------------------
__global__ void k_rope_table(float* __restrict__ cosT, float* __restrict__ sinT) {
  int i = blockIdx.x * blockDim.x + threadIdx.x;
  int tpos = i >> 6, f = i & 63;
  double inv = exp(-0.14391156831212787 * (double)f);
  float ang = (float)tpos * (float)inv;
  cosT[i] = cosf(ang);
  sinT[i] = sinf(ang);
}

// ---------------------------------------------------------------------------
__global__ __launch_bounds__(256) void k_qknorm_rope(
    const unsigned short* __restrict__ QKVZ,
    unsigned short* __restrict__ Qo, unsigned short* __restrict__ Ko,
    const float* __restrict__ qw, const float* __restrict__ kw,
    const float* __restrict__ cosT, const float* __restrict__ sinT) {
  int gid = blockIdx.x * 4 + (threadIdx.x >> 6);
  int lane = threadIdx.x & 63;
  int tok = gid / 20, hh = gid % 20;
  const unsigned short* p; const float* w; unsigned short* o;
  if (hh < 16) { p = QKVZ + (size_t)tok * 5120 + hh * 128; w = qw;
                 o = Qo + (size_t)tok * 2048 + hh * 128; }
  else         { p = QKVZ + (size_t)tok * 5120 + 2048 + (hh - 16) * 128; w = kw;
                 o = Ko + (size_t)tok * 512 + (hh - 16) * 128; }
  float x1 = bf2f(p[lane]), x2 = bf2f(p[lane + 64]);
  float ss = x1 * x1 + x2 * x2;
#pragma unroll
  for (int m = 1; m < 64; m <<= 1) ss += __shfl_xor(ss, m);
  float r = rsqrtf(ss * (1.0f / 128.0f) + 1e-6f);
  float n1 = x1 * r * (1.f + w[lane]);
  float n2 = x2 * r * (1.f + w[lane + 64]);
  int s = tok & 1023;
  float c = cosT[s * 64 + lane], sn = sinT[s * 64 + lane];
  o[lane]      = f2bf(n1 * c - n2 * sn);
  o[lane + 64] = f2bf(n2 * c + n1 * sn);
}

// ---------------------------------------------------------------------------
__global__ __launch_bounds__(256) void k_transpose_v(const unsigned short* __restrict__ QKVZ,
                                                     unsigned short* __restrict__ Vt) {
  __shared__ unsigned short Vl[128 * 66];
  const int t = threadIdx.x;
  const int key0 = blockIdx.x * 64, kvh = blockIdx.y, b = blockIdx.z;
#pragma unroll
  for (int i = 0; i < 4; ++i) {
    int g = i * 256 + t;
    int key = g >> 4, dc = (g & 15) * 8;
    s16x8 v = *(const s16x8*)&QKVZ[(size_t)(b * 1024 + key0 + key) * 5120 + 2560 + kvh * 128 + dc];
#pragma unroll
    for (int j = 0; j < 8; ++j) Vl[(dc + j) * 66 + key] = (unsigned short)v[j];
  }
  __syncthreads();
#pragma unroll
  for (int i = 0; i < 8; ++i) {
    int g = i * 256 + t;
    int d = g >> 4, kc = g & 15;
    u16x4 o;
#pragma unroll
    for (int j = 0; j < 4; ++j) o[j] = Vl[d * 66 + kc * 4 + j];
    *(u16x4*)&Vt[((size_t)(b * 4 + kvh) * 128 + d) * 1024 + key0 + kc * 4] = o;
  }
}

// ---------------------------------------------------------------------------
// 256x256 GEMM, BK=64, 8 waves (2M x 4N), per-wave 128x64 out (8x4 frags).
// m201-style schedule: per phase {ds_read subtile; stage issue; barrier;
// MFMA x16; barrier}; ONE vmcnt(8) per K-tile at phase 3 (2-K-tile lookahead,
// 8 staging loads/wave/K-tile). Granule-XOR swizzle (0 bank conflicts, r6).
// EPI 2: store bf16.  EPI 4: in-place bf16( silu(Cb[idx]) * acc ).
// ---------------------------------------------------------------------------
template <int EPI>
__global__ __launch_bounds__(512) void k_gemm256(
    const unsigned short* __restrict__ A, const unsigned short* __restrict__ B,
    unsigned short* __restrict__ Cb, int M, int N, int K) {
  __shared__ unsigned short As[2][256][64];
  __shared__ unsigned short Bs[2][256][64];

  const int t = threadIdx.x, lane = t & 63, w = t >> 6;
  const int wr = w >> 2, wc = w & 3;          // 2M x 4N wave grid
  const int l15 = lane & 15, l4 = lane >> 4;
  const int xg = l15 & 7;
  const int hb = wc >> 1, cl = wc & 1;

  // XCD-chunk + GM=8 supertile raster (nwg % 8 == 0)
  const int nbx = gridDim.x;
  const int nwg = nbx * gridDim.y;
  const int bid = blockIdx.y * nbx + blockIdx.x;
  const int sw = (bid & 7) * (nwg >> 3) + (bid >> 3);
  const int tpg = 8 * nbx;
  const int mi_ = (sw / tpg) * 8 + (sw & 7);
  const int ni_ = (sw % tpg) >> 3;
  const int m0 = mi_ * 256, n0 = ni_ * 256;

  const int NT = K >> 6;

  // staging: source granule pre-swizzled so read-side XOR recovers linear k
  auto stageA = [&](int tt, int pm) {   // pm=0: rows {0-63,128-191}; pm=1: rest
    int dd = tt & 1;
#pragma unroll
    for (int c = 0; c < 2; ++c) {
      int r0 = wr * 128 + pm * 64 + wc * 16 + c * 8;
      int r = r0 + (lane >> 3);
      int gs = (lane & 7) ^ (r & 7);
      gload16(A + (size_t)(m0 + r) * K + tt * 64 + gs * 8, (void*)&As[dd][r0][0]);
    }
  };
  auto stageB = [&](int tt, int pn) {   // pn strip: (row&63) in [pn*32, +32)
    int dd = tt & 1;
#pragma unroll
    for (int c = 0; c < 2; ++c) {
      int r0 = hb * 128 + cl * 64 + pn * 32 + wr * 16 + c * 8;
      int r = r0 + (lane >> 3);
      int gs = (lane & 7) ^ (r & 7);
      gload16(B + (size_t)(n0 + r) * K + tt * 64 + gs * 8, (void*)&Bs[dd][r0][0]);
    }
  };

  // prologue: tiles 0 and 1 (8 loads each)
  stageA(0, 0); stageB(0, 0); stageB(0, 1); stageA(0, 1);
  stageA(1, 0); stageB(1, 0); stageB(1, 1); stageA(1, 1);

  f32x4 acc[8][4] = {};

  WAITV8();                       // tile 0 landed (tile 1's 8 may remain)
  __builtin_amdgcn_s_barrier();

  for (int u = 0; u < NT; ++u) {
    const int cur = u & 1;
    const bool deep = (u + 2 < NT);
    s16x8 afL[4][2], afH[4][2], bf0[2][2], bf1[2][2];

    // ---- phase 0: read afL(8) + bf0(4); MFMA quadrant (low, n0-1) ----------
#pragma unroll
    for (int i = 0; i < 4; ++i) {
      int row = wr * 128 + i * 16 + l15;
      afL[i][0] = *(const s16x8*)&As[cur][row][(l4 ^ xg) * 8];
      afL[i][1] = *(const s16x8*)&As[cur][row][((l4 ^ xg) ^ 4) * 8];
    }
#pragma unroll
    for (int n = 0; n < 2; ++n) {
      int row = wc * 64 + n * 16 + l15;
      bf0[n][0] = *(const s16x8*)&Bs[cur][row][(l4 ^ xg) * 8];
      bf0[n][1] = *(const s16x8*)&Bs[cur][row][((l4 ^ xg) ^ 4) * 8];
    }
    __builtin_amdgcn_s_barrier();
    __builtin_amdgcn_s_setprio(1);
#pragma unroll
    for (int i = 0; i < 4; ++i)
#pragma unroll
      for (int n = 0; n < 2; ++n) {
        acc[i][n] = MFMA_BF16(afL[i][0], bf0[n][0], acc[i][n], 0, 0, 0);
        acc[i][n] = MFMA_BF16(afL[i][1], bf0[n][1], acc[i][n], 0, 0, 0);
      }
    __builtin_amdgcn_s_setprio(0);
    __builtin_amdgcn_s_barrier();

    // ---- phase 1: read bf1(4); stage A-low(u+2); MFMA (low, n2-3) ----------
#pragma unroll
    for (int n = 0; n < 2; ++n) {
      int row = wc * 64 + (2 + n) * 16 + l15;
      bf1[n][0] = *(const s16x8*)&Bs[cur][row][(l4 ^ xg) * 8];
      bf1[n][1] = *(const s16x8*)&Bs[cur][row][((l4 ^ xg) ^ 4) * 8];
    }
    if (deep) stageA(u + 2, 0);
    __builtin_amdgcn_s_barrier();
    __builtin_amdgcn_s_setprio(1);
#pragma unroll
    for (int i = 0; i < 4; ++i)
#pragma unroll
      for (int n = 0; n < 2; ++n) {
        acc[i][2 + n] = MFMA_BF16(afL[i][0], bf1[n][0], acc[i][2 + n], 0, 0, 0);
        acc[i][2 + n] = MFMA_BF16(afL[i][1], bf1[n][1], acc[i][2 + n], 0, 0, 0);
      }
    __builtin_amdgcn_s_setprio(0);
    __builtin_amdgcn_s_barrier();

    // ---- phase 2: read afH(8); stage B(u+2); MFMA (high, n2-3) -------------
#pragma unroll
    for (int i = 0; i < 4; ++i) {
      int row = wr * 128 + 64 + i * 16 + l15;
      afH[i][0] = *(const s16x8*)&As[cur][row][(l4 ^ xg) * 8];
      afH[i][1] = *(const s16x8*)&As[cur][row][((l4 ^ xg) ^ 4) * 8];
    }
    if (deep) { stageB(u + 2, 0); stageB(u + 2, 1); }
    __builtin_amdgcn_s_barrier();
    __builtin_amdgcn_s_setprio(1);
#pragma unroll
    for (int i = 0; i < 4; ++i)
#pragma unroll
      for (int n = 0; n < 2; ++n) {
        acc[4 + i][2 + n] = MFMA_BF16(afH[i][0], bf1[n][0], acc[4 + i][2 + n], 0, 0, 0);
        acc[4 + i][2 + n] = MFMA_BF16(afH[i][1], bf1[n][1], acc[4 + i][2 + n], 0, 0, 0);
      }
    __builtin_amdgcn_s_setprio(0);
    __builtin_amdgcn_s_barrier();

    // ---- phase 3: stage A-high(u+2); vmcnt fence for next tile; MFMA -------
    if (deep) stageA(u + 2, 1);
    if (deep) WAITV8(); else WAITV0();
    __builtin_amdgcn_s_barrier();
    __builtin_amdgcn_s_setprio(1);
#pragma unroll
    for (int i = 0; i < 4; ++i)
#pragma unroll
      for (int n = 0; n < 2; ++n) {
        acc[4 + i][n] = MFMA_BF16(afH[i][0], bf0[n][0], acc[4 + i][n], 0, 0, 0);
        acc[4 + i][n] = MFMA_BF16(afH[i][1], bf0[n][1], acc[4 + i][n], 0, 0, 0);
      }
    __builtin_amdgcn_s_setprio(0);
    __builtin_amdgcn_s_barrier();
  }

  // ---- epilogue: C layout col = l15, row = l4*4 + j
#pragma unroll
  for (int mi = 0; mi < 8; ++mi)
#pragma unroll
    for (int ni = 0; ni < 4; ++ni) {
      int col = n0 + wc * 64 + ni * 16 + l15;
#pragma unroll
      for (int j = 0; j < 4; ++j) {
        int row = m0 + wr * 128 + mi * 16 + l4 * 4 + j;
        size_t idx = (size_t)row * N + col;
        float g = acc[mi][ni][j];
        if constexpr (EPI == 2) {
          Cb[idx] = f2bf(g);
        } else {
          float gv = bf2f(Cb[idx]);
          float sg = gv / (1.f + __expf(-gv));
          Cb[idx] = f2bf(sg * g);
        }
      }
    }
}

// ---------------------------------------------------------------------------
// 128x128 2-phase GEMM (Wo / Wd). EPI 1: f32 + residual.
// ---------------------------------------------------------------------------
template <int EPI>
__global__ __launch_bounds__(256) void k_gemm_bt(
    const unsigned short* __restrict__ A, const unsigned short* __restrict__ B,
    float* __restrict__ Cf, unsigned short* __restrict__ Cb,
    const float* __restrict__ res,
    int M, int N, int K) {
  __shared__ unsigned short As[2][128 * 32];
  __shared__ unsigned short Bs[2][128 * 32];

  const int t = threadIdx.x, lane = t & 63, w = t >> 6;
  const int wr = w >> 1, wc = w & 1;
  const int nbx = gridDim.x;
  const int nwg = nbx * gridDim.y;
  const int bid = blockIdx.y * nbx + blockIdx.x;
  const int sw = (bid & 7) * (nwg >> 3) + (bid >> 3);
  const int tpg = 8 * nbx;
  const int mi = (sw / tpg) * 8 + (sw & 7);
  const int ni = (sw % tpg) >> 3;
  const int m0 = mi * 128, n0 = ni * 128;

  f32x4 acc[4][4] = {};

  const int srow = lane >> 2;
  const int scol = (lane & 3) * 8;

  auto stage = [&](int kk, int sel) {
#pragma unroll
    for (int r = 0; r < 2; ++r) {
      int row = 16 * w + srow + 64 * r;
      gload16(A + (size_t)(m0 + row) * K + kk + scol, (void*)&As[sel][w * 512 + r * 2048]);
      gload16(B + (size_t)(n0 + row) * K + kk + scol, (void*)&Bs[sel][w * 512 + r * 2048]);
    }
  };

  stage(0, 0);
  __syncthreads();

  const int nk = K >> 5;
  for (int tk = 0; tk < nk; ++tk) {
    const int cur = tk & 1;
    if (tk + 1 < nk) stage((tk + 1) << 5, cur ^ 1);

    s16x8 af[4], bf_[4];
#pragma unroll
    for (int i = 0; i < 4; ++i) {
      af[i]  = *(const s16x8*)&As[cur][(wr * 64 + i * 16 + (lane & 15)) * 32 + (lane >> 4) * 8];
      bf_[i] = *(const s16x8*)&Bs[cur][(wc * 64 + i * 16 + (lane & 15)) * 32 + (lane >> 4) * 8];
    }
#pragma unroll
    for (int mi2 = 0; mi2 < 4; ++mi2)
#pragma unroll
      for (int ni2 = 0; ni2 < 4; ++ni2)
        acc[mi2][ni2] = MFMA_BF16(af[mi2], bf_[ni2], acc[mi2][ni2], 0, 0, 0);
    __syncthreads();
  }

  const int er = (lane >> 4) * 4;
  const int ec = lane & 15;
#pragma unroll
  for (int mi2 = 0; mi2 < 4; ++mi2)
#pragma unroll
    for (int ni2 = 0; ni2 < 4; ++ni2) {
      int col = n0 + wc * 64 + ni2 * 16 + ec;
#pragma unroll
      for (int j = 0; j < 4; ++j) {
        int row = m0 + wr * 64 + mi2 * 16 + er + j;
        size_t idx = (size_t)row * N + col;
        float g = acc[mi2][ni2][j];
        if constexpr (EPI == 0) {
          Cf[idx] = g;
        } else if constexpr (EPI == 1) {
          Cf[idx] = g + res[idx];
        } else if constexpr (EPI == 2) {
          Cb[idx] = f2bf(g);
        } else {
          float gv = bf2f(Cb[idx]);
          float sg = gv / (1.f + __expf(-gv));
          Cb[idx] = f2bf(sg * g);
        }
      }
    }
}

// ---------------------------------------------------------------------------
// Causal GQA attention, bf16 MFMA flash (unchanged).
// ---------------------------------------------------------------------------
__global__ __launch_bounds__(256) void k_attn_mfma(
    const unsigned short* __restrict__ Qb,
    const unsigned short* __restrict__ Kb,
    const unsigned short* __restrict__ Vt,
    const unsigned short* __restrict__ Zb,
    unsigned short* __restrict__ AO) {
  __shared__ unsigned short Qs[64 * 128];
  __shared__ unsigned short Ks[64 * 128];
  __shared__ unsigned short Vts[128 * 64];
  __shared__ unsigned short Ps[4][16 * 64];

  const int t = threadIdx.x, lane = t & 63, w = t >> 6;
  const int l15 = lane & 15, l4 = lane >> 4;
  const int qt = (int)gridDim.x - 1 - (int)blockIdx.x;
  const int qs0 = qt * 64;
  const int h = blockIdx.y, b = blockIdx.z;
  const int kv = h >> 2;

  {
    const unsigned short* qb = Qb + (size_t)(b * 1024 + qs0) * 2048 + h * 128;
#pragma unroll
    for (int r = 0; r < 4; ++r) {
      int row = r * 16 + w * 4 + (lane >> 4);
      int cp = lane & 15;
      int c = (cp & 8) | ((cp & 7) ^ (row & 7));
      gload16(qb + (size_t)row * 2048 + c * 8, (void*)&Qs[(r * 256 + w * 64) * 8]);
    }
  }

  auto stageKV = [&](int j0) {
    const unsigned short* kb = Kb + (size_t)(b * 1024 + j0) * 512 + kv * 128;
#pragma unroll
    for (int r = 0; r < 4; ++r) {
      int row = r * 16 + w * 4 + (lane >> 4);
      int cp = lane & 15;
      int c = (cp & 8) | ((cp & 7) ^ (row & 7));
      gload16(kb + (size_t)row * 512 + c * 8, (void*)&Ks[(r * 256 + w * 64) * 8]);
    }
    const unsigned short* vb = Vt + (size_t)(b * 4 + kv) * 131072 + j0;
#pragma unroll
    for (int r = 0; r < 4; ++r) {
      int row = r * 32 + w * 8 + (lane >> 3);
      int cp = lane & 7;
      int c = cp ^ (row & 7);
      gload16(vb + (size_t)row * 1024 + c * 8, (void*)&Vts[(r * 256 + w * 64) * 8]);
    }
  };

  stageKV(0);
  __syncthreads();

  s16x8 qf[4];
#pragma unroll
  for (int ks = 0; ks < 4; ++ks) {
    int R = w * 16 + l15;
    int c = ks * 4 + l4;
    int cp = (c & 8) | ((c & 7) ^ (R & 7));
    qf[ks] = *(const s16x8*)&Qs[R * 128 + cp * 8];
  }

  f32x4 O[8] = {};
  f32x4 mrow = {-1e30f, -1e30f, -1e30f, -1e30f};
  f32x4 lrow = {0.f, 0.f, 0.f, 0.f};
  const float scale = 0.088388347648318447f;

  for (int tile = 0; tile <= qt; ++tile) {
    f32x4 sc[4] = {};
#pragma unroll
    for (int ks = 0; ks < 4; ++ks) {
#pragma unroll
      for (int kt = 0; kt < 4; ++kt) {
        int R = kt * 16 + l15;
        int c = ks * 4 + l4;
        int cp = (c & 8) | ((c & 7) ^ (R & 7));
        s16x8 kf = *(const s16x8*)&Ks[R * 128 + cp * 8];
        sc[kt] = MFMA_BF16(qf[ks], kf, sc[kt], 0, 0, 0);
      }
    }
    const bool diag = (tile == qt);
#pragma unroll
    for (int kt = 0; kt < 4; ++kt) {
      int key = kt * 16 + l15;
#pragma unroll
      for (int j = 0; j < 4; ++j) {
        float s = sc[kt][j] * scale;
        if (diag && key > (w * 16 + l4 * 4 + j)) s = -1e30f;
        sc[kt][j] = s;
      }
    }
    f32x4 mt;
#pragma unroll
    for (int j = 0; j < 4; ++j)
      mt[j] = fmaxf(fmaxf(sc[0][j], sc[1][j]), fmaxf(sc[2][j], sc[3][j]));
#pragma unroll
    for (int msk = 1; msk < 16; msk <<= 1)
#pragma unroll
      for (int j = 0; j < 4; ++j) mt[j] = fmaxf(mt[j], __shfl_xor(mt[j], msk));
    f32x4 mnew, rs;
#pragma unroll
    for (int j = 0; j < 4; ++j) {
      mnew[j] = fmaxf(mrow[j], mt[j]);
      rs[j] = __expf(mrow[j] - mnew[j]);
    }
    f32x4 psum = {0.f, 0.f, 0.f, 0.f};
    unsigned short* pw = &Ps[w][0];
#pragma unroll
    for (int kt = 0; kt < 4; ++kt) {
      int kg = kt * 2 + (l15 >> 3), ke = l15 & 7;
#pragma unroll
      for (int j = 0; j < 4; ++j) {
        float p = __expf(sc[kt][j] - mnew[j]);
        psum[j] += p;
        int q = l4 * 4 + j;
        pw[q * 64 + ((kg ^ (q & 7)) * 8) + ke] = f2bf(p);
      }
    }
#pragma unroll
    for (int msk = 1; msk < 16; msk <<= 1)
#pragma unroll
      for (int j = 0; j < 4; ++j) psum[j] += __shfl_xor(psum[j], msk);
    mrow = mnew;
#pragma unroll
    for (int j = 0; j < 4; ++j) lrow[j] = lrow[j] * rs[j] + psum[j];
#pragma unroll
    for (int dt = 0; dt < 8; ++dt) O[dt] *= rs;
#pragma unroll
    for (int js = 0; js < 2; ++js) {
      int cpp = (js * 4 + l4) ^ (l15 & 7);
      s16x8 pf = *(const s16x8*)&Ps[w][l15 * 64 + cpp * 8];
#pragma unroll
      for (int dt = 0; dt < 8; ++dt) {
        int D = dt * 16 + l15;
        s16x8 vf = *(const s16x8*)&Vts[D * 64 + cpp * 8];
        O[dt] = MFMA_BF16(pf, vf, O[dt], 0, 0, 0);
      }
    }
    __syncthreads();
    if (tile < qt) stageKV((tile + 1) * 64);
    __syncthreads();
  }

  f32x4 linv;
#pragma unroll
  for (int j = 0; j < 4; ++j) linv[j] = 1.f / lrow[j];
  const int tok0 = b * 1024 + qs0 + w * 16 + l4 * 4;
#pragma unroll
  for (int dt = 0; dt < 8; ++dt) {
    int d = dt * 16 + l15;
#pragma unroll
    for (int j = 0; j < 4; ++j) {
      size_t zidx = (size_t)(tok0 + j) * 5120 + h * 128 + d;
      size_t aidx = (size_t)(tok0 + j) * 2048 + h * 128 + d;
      float z = bf2f(Zb[zidx]);
      float o = O[dt][j] * linv[j];
      AO[aidx] = f2bf(o / (1.f + __expf(-z)));
    }
  }
}

// ---------------------------------------------------------------------------
// launcher
// ---------------------------------------------------------------------------
extern "C" void kernel_launch(void* const* d_in, const int* in_sizes, int n_in,
                              void* d_out, int out_size, void* d_ws, size_t ws_size,
                              hipStream_t stream) {
  const float* x       = (const float*)d_in[0];
  const float* in_ln   = (const float*)d_in[1];
  const float* Wq      = (const float*)d_in[2];
  const float* Wk      = (const float*)d_in[3];
  const float* Wv      = (const float*)d_in[4];
  const float* Wz      = (const float*)d_in[5];
  const float* Wo      = (const float*)d_in[6];
  const float* qn_w    = (const float*)d_in[7];
  const float* kn_w    = (const float*)d_in[8];
  const float* post_ln = (const float*)d_in[9];
  const float* Wg      = (const float*)d_in[10];
  const float* Wu      = (const float*)d_in[11];
  const float* Wd      = (const float*)d_in[12];

  const int T = 4096;

  char* ws = (char*)d_ws;
  size_t off = 0;
  auto alloc = [&](size_t bytes) -> void* {
    off = (off + 255) & ~(size_t)255;
    void* p = ws + off;
    off += bytes;
    return p;
  };

  unsigned short* Wqkvz_b = (unsigned short*)alloc((size_t)5120 * 2048 * 2);
  unsigned short* Wo_b = (unsigned short*)alloc((size_t)2048 * 2048 * 2);
  unsigned short* Wg_b = (unsigned short*)alloc((size_t)8192 * 2048 * 2);
  unsigned short* Wu_b = (unsigned short*)alloc((size_t)8192 * 2048 * 2);
  unsigned short* Wd_b = (unsigned short*)alloc((size_t)2048 * 8192 * 2);

  char* R = (char*)alloc((size_t)64 * 1024 * 1024);
  unsigned short* qkvz_bf = (unsigned short*)R;
  unsigned short* h_bf    = (unsigned short*)(R + (size_t)40 * 1024 * 1024);
  unsigned short* gu_bf   = (unsigned short*)R;
  unsigned short* ao_bf   = h_bf;

  float* x2 = (float*)alloc((size_t)T * 2048 * 4);
  char* x2c = (char*)x2;
  unsigned short* vt_bf = (unsigned short*)(x2c);
  unsigned short* k_bf  = (unsigned short*)(x2c + 4194304);
  unsigned short* q_bf  = (unsigned short*)(x2c + 8388608);

  unsigned short* h2_bf = (unsigned short*)alloc((size_t)T * 2048 * 2);
  float* cosT = (float*)alloc((size_t)1024 * 64 * 4);
  float* sinT = (float*)alloc((size_t)1024 * 64 * 4);

  auto cvt = [&](const float* s, unsigned short* d, size_t n) {
    int n4 = (int)(n / 4);
    int blocks = (n4 + 255) / 256;
    if (blocks > 2048) blocks = 2048;
    k_f32_to_bf16<<<blocks, 256, 0, stream>>>(s, d, n4);
  };
  cvt(Wq, Wqkvz_b, (size_t)2048 * 2048);
  cvt(Wk, Wqkvz_b + (size_t)2048 * 2048, (size_t)512 * 2048);
  cvt(Wv, Wqkvz_b + (size_t)2560 * 2048, (size_t)512 * 2048);
  cvt(Wz, Wqkvz_b + (size_t)3072 * 2048, (size_t)2048 * 2048);
  cvt(Wo, Wo_b, (size_t)2048 * 2048);
  cvt(Wg, Wg_b, (size_t)8192 * 2048);
  cvt(Wu, Wu_b, (size_t)8192 * 2048);
  cvt(Wd, Wd_b, (size_t)2048 * 8192);

  k_rope_table<<<256, 256, 0, stream>>>(cosT, sinT);

  // h = rmsnorm(x, in_ln)
  k_rmsnorm<<<T, 256, 0, stream>>>(x, in_ln, h_bf);

  // fused QKVZ projection: [4096][5120] bf16 (256² 4-phase)
  k_gemm256<2><<<dim3(20, 16), 512, 0, stream>>>(h_bf, Wqkvz_b, qkvz_bf, T, 5120, 2048);

  // per-head q/k RMSNorm + RoPE -> bf16
  k_qknorm_rope<<<20480, 256, 0, stream>>>(qkvz_bf, q_bf, k_bf, qn_w, kn_w, cosT, sinT);

  // V -> V^T bf16 per (b,kv)
  k_transpose_v<<<dim3(16, 4, 4), 256, 0, stream>>>(qkvz_bf, vt_bf);

  // causal GQA attention (MFMA) + sigmoid(z) gate -> ao_bf
  k_attn_mfma<<<dim3(16, 16, 4), 256, 0, stream>>>(q_bf, k_bf, vt_bf, qkvz_bf + 3072, ao_bf);

  // x2 = x + ao @ Wo^T  (128² kernel: 256²-grid would underfill at N=2048)
  k_gemm_bt<1><<<dim3(16, 32), 256, 0, stream>>>(ao_bf, Wo_b, x2, nullptr, x, T, 2048, 2048);

  // h2 = rmsnorm(x2, post_ln)
  k_rmsnorm<<<T, 256, 0, stream>>>(x2, post_ln, h2_bf);

  // gu = h2 @ Wg^T  (bf16, 256² 4-phase)
  k_gemm256<2><<<dim3(32, 16), 512, 0, stream>>>(h2_bf, Wg_b, gu_bf, T, 8192, 2048);

  // gu = silu(gu) * (h2 @ Wu^T)  (in place, 256² 4-phase)
  k_gemm256<4><<<dim3(32, 16), 512, 0, stream>>>(h2_bf, Wu_b, gu_bf, T, 8192, 2048);

  // out = x2 + gu @ Wd^T  (128² kernel)
  k_gemm_bt<1><<<dim3(16, 32), 256, 0, stream>>>(gu_bf, Wd_b, (float*)d_out, nullptr, x2, T, 2048, 8192);
}